// Round 1
// baseline (10950.171 us; speedup 1.0000x reference)
//
#include <hip/hip_runtime.h>

#define N_NODES 100000
#define N_EDGES 1600000
#define PITCH 68  // floats per LDS row: 16B-aligned, conflict-free b128 pattern

// wave-uniform channel-chunk base (wave w owns channels [16w, 16w+16))
__device__ __forceinline__ int wave_c0() {
  return __builtin_amdgcn_readfirstlane((int)((threadIdx.x >> 6) << 4));
}

// acc[j] = (BIAS? bias[c0+j]:0) + sum_k Alds[lane][k] * W[k*64 + c0 + j], opt relu.
// W/bias indices are wave-uniform -> compiler emits scalar loads, FMA uses SGPR src.
template<bool RELU, bool BIAS>
__device__ __forceinline__ void wave_gemm16(const float* Alds, int lane, int c0,
                                            const float* __restrict__ W,
                                            const float* __restrict__ bias,
                                            float acc[16]) {
#pragma unroll
  for (int j = 0; j < 16; ++j) acc[j] = BIAS ? bias[c0 + j] : 0.0f;
  const float* arow = Alds + lane * PITCH;
#pragma unroll
  for (int k = 0; k < 64; k += 4) {
    const float4 a4 = *reinterpret_cast<const float4*>(arow + k);
    const float av[4] = {a4.x, a4.y, a4.z, a4.w};
#pragma unroll
    for (int kk = 0; kk < 4; ++kk) {
#pragma unroll
      for (int j = 0; j < 16; ++j)
        acc[j] = fmaf(av[kk], W[(k + kk) * 64 + c0 + j], acc[j]);
    }
  }
  if (RELU) {
#pragma unroll
    for (int j = 0; j < 16; ++j) acc[j] = fmaxf(acc[j], 0.0f);
  }
}

__device__ __forceinline__ void store4x4(float* dst, const float a[16]) {
#pragma unroll
  for (int q = 0; q < 4; ++q)
    *reinterpret_cast<float4*>(dst + q * 4) =
        make_float4(a[q * 4], a[q * 4 + 1], a[q * 4 + 2], a[q * 4 + 3]);
}

// ---- Kernel A: h = relu(x@W_in+b_in); ad=h@W_dst; as=h@W_src; v=h@W_lin ----
__global__ __launch_bounds__(256) void node_proj_kernel(
    const float* __restrict__ x, const float* __restrict__ W_in,
    const float* __restrict__ b_in, const float* __restrict__ W_lin,
    const float* __restrict__ W_src, const float* __restrict__ W_dst,
    float* __restrict__ ad, float* __restrict__ as_, float* __restrict__ v) {
  __shared__ __align__(16) float A[64 * PITCH];
  const int tid = threadIdx.x, lane = tid & 63, c0 = wave_c0();
  const int n0 = blockIdx.x * 64;
  // stage x tile (float4, coalesced), zero-pad past N
#pragma unroll
  for (int i = 0; i < 4; ++i) {
    int idx4 = tid + i * 256;            // 0..1023 float4s
    int e = idx4 >> 4, k4 = (idx4 & 15) * 4;
    int n = n0 + e;
    float4 val = make_float4(0.f, 0.f, 0.f, 0.f);
    if (n < N_NODES) val = *reinterpret_cast<const float4*>(x + (size_t)n * 64 + k4);
    *reinterpret_cast<float4*>(&A[e * PITCH + k4]) = val;
  }
  __syncthreads();
  float h[16];
  wave_gemm16<true, true>(A, lane, c0, W_in, b_in, h);
  __syncthreads();
  store4x4(&A[lane * PITCH + c0], h);
  __syncthreads();
  float o1[16], o2[16], o3[16];
  wave_gemm16<false, false>(A, lane, c0, W_dst, nullptr, o1);
  wave_gemm16<false, false>(A, lane, c0, W_src, nullptr, o2);
  wave_gemm16<false, false>(A, lane, c0, W_lin, nullptr, o3);
  const int n = n0 + lane;
  if (n < N_NODES) {
    store4x4(ad + (size_t)n * 64 + c0, o1);
    store4x4(as_ + (size_t)n * 64 + c0, o2);
    store4x4(v + (size_t)n * 64 + c0, o3);
  }
}

// ---- Kernel B: per-edge MLPs + exp + atomic scatter of num/den ----
__global__ __launch_bounds__(256) void edge_kernel(
    const int* __restrict__ ei, const float* __restrict__ pos,
    const float* __restrict__ Wp1, const float* __restrict__ bp1,
    const float* __restrict__ Wp2, const float* __restrict__ bp2,
    const float* __restrict__ Wa1, const float* __restrict__ ba1,
    const float* __restrict__ Wa2, const float* __restrict__ ba2,
    const float* __restrict__ ad, const float* __restrict__ as_,
    const float* __restrict__ v, float* __restrict__ num,
    float* __restrict__ den) {
  __shared__ __align__(16) float A[64 * PITCH];
  const int tid = threadIdx.x, lane = tid & 63, c0 = wave_c0();
  const int e = blockIdx.x * 64 + lane;  // E divisible by 64
  const int s = ei[e];
  const int d = ei[N_EDGES + e];
  const float2 pd = reinterpret_cast<const float2*>(pos)[d];
  const float2 ps = reinterpret_cast<const float2*>(pos)[s];
  const float dx = pd.x - ps.x, dy = pd.y - ps.y;
  // hp chunk (pos-MLP layer 1) -> LDS
#pragma unroll
  for (int q = 0; q < 4; ++q) {
    float t4[4];
#pragma unroll
    for (int u = 0; u < 4; ++u) {
      int hh = c0 + q * 4 + u;
      t4[u] = fmaxf(fmaf(dx, Wp1[hh], fmaf(dy, Wp1[64 + hh], bp1[hh])), 0.0f);
    }
    *reinterpret_cast<float4*>(&A[lane * PITCH + c0 + q * 4]) =
        make_float4(t4[0], t4[1], t4[2], t4[3]);
  }
  __syncthreads();
  float delta[16];
  wave_gemm16<true, true>(A, lane, c0, Wp2, bp2, delta);
  __syncthreads();
  // a_in = ad[d] - as[s] + delta -> LDS
#pragma unroll
  for (int q = 0; q < 4; ++q) {
    float4 a4 = *reinterpret_cast<const float4*>(ad + (size_t)d * 64 + c0 + q * 4);
    float4 b4 = *reinterpret_cast<const float4*>(as_ + (size_t)s * 64 + c0 + q * 4);
    float4 r;
    r.x = a4.x - b4.x + delta[q * 4 + 0];
    r.y = a4.y - b4.y + delta[q * 4 + 1];
    r.z = a4.z - b4.z + delta[q * 4 + 2];
    r.w = a4.w - b4.w + delta[q * 4 + 3];
    *reinterpret_cast<float4*>(&A[lane * PITCH + c0 + q * 4]) = r;
  }
  __syncthreads();
  float ha[16];
  wave_gemm16<true, true>(A, lane, c0, Wa1, ba1, ha);
  __syncthreads();
  store4x4(&A[lane * PITCH + c0], ha);
  __syncthreads();
  float aat[16];
  wave_gemm16<true, true>(A, lane, c0, Wa2, ba2, aat);
  // epilogue: ex = exp(a) (amax skipped: a in [0,~7], fp32-safe; softmax invariant)
#pragma unroll
  for (int q = 0; q < 4; ++q) {
    float4 v4 = *reinterpret_cast<const float4*>(v + (size_t)s * 64 + c0 + q * 4);
    const float vv[4] = {v4.x, v4.y, v4.z, v4.w};
#pragma unroll
    for (int u = 0; u < 4; ++u) {
      int j = q * 4 + u;
      float ex = __expf(aat[j]);
      atomicAdd(&num[(size_t)d * 64 + c0 + j], ex * (vv[u] + delta[j]));
      atomicAdd(&den[(size_t)d * 64 + c0 + j], ex);
    }
  }
}

// ---- Kernel C: out = relu((num/(den+1e-16)) @ W_out + b_out) ----
__global__ __launch_bounds__(256) void out_kernel(
    const float* __restrict__ num, const float* __restrict__ den,
    const float* __restrict__ W_out, const float* __restrict__ b_out,
    float* __restrict__ out) {
  __shared__ __align__(16) float A[64 * PITCH];
  const int tid = threadIdx.x, lane = tid & 63, c0 = wave_c0();
  const int n0 = blockIdx.x * 64;
#pragma unroll
  for (int i = 0; i < 4; ++i) {
    int idx4 = tid + i * 256;
    int e = idx4 >> 4, k4 = (idx4 & 15) * 4;
    int n = n0 + e;
    float4 val = make_float4(0.f, 0.f, 0.f, 0.f);
    if (n < N_NODES) {
      float4 nu = *reinterpret_cast<const float4*>(num + (size_t)n * 64 + k4);
      float4 de = *reinterpret_cast<const float4*>(den + (size_t)n * 64 + k4);
      val.x = nu.x / (de.x + 1e-16f);
      val.y = nu.y / (de.y + 1e-16f);
      val.z = nu.z / (de.z + 1e-16f);
      val.w = nu.w / (de.w + 1e-16f);
    }
    *reinterpret_cast<float4*>(&A[e * PITCH + k4]) = val;
  }
  __syncthreads();
  float o[16];
  wave_gemm16<true, true>(A, lane, c0, W_out, b_out, o);
  const int n = n0 + lane;
  if (n < N_NODES) store4x4(out + (size_t)n * 64 + c0, o);
}

extern "C" void kernel_launch(void* const* d_in, const int* in_sizes, int n_in,
                              void* d_out, int out_size, void* d_ws,
                              size_t ws_size, hipStream_t stream) {
  const float* x     = (const float*)d_in[0];
  const float* pos   = (const float*)d_in[1];
  const int*   ei    = (const int*)d_in[2];
  const float* W_in  = (const float*)d_in[3];
  const float* b_in  = (const float*)d_in[4];
  const float* W_lin = (const float*)d_in[5];
  const float* W_src = (const float*)d_in[6];
  const float* W_dst = (const float*)d_in[7];
  const float* Wp1   = (const float*)d_in[8];
  const float* bp1   = (const float*)d_in[9];
  const float* Wp2   = (const float*)d_in[10];
  const float* bp2   = (const float*)d_in[11];
  const float* Wa1   = (const float*)d_in[12];
  const float* ba1   = (const float*)d_in[13];
  const float* Wa2   = (const float*)d_in[14];
  const float* ba2   = (const float*)d_in[15];
  const float* W_out = (const float*)d_in[16];
  const float* b_out = (const float*)d_in[17];
  float* out = (float*)d_out;

  float* ws = (float*)d_ws;
  const size_t NC = (size_t)N_NODES * 64;
  float* ad  = ws;
  float* as_ = ws + NC;
  float* v   = ws + 2 * NC;
  float* num = ws + 3 * NC;
  float* den = ws + 4 * NC;

  hipMemsetAsync(num, 0, 2 * NC * sizeof(float), stream);  // zero num+den
  node_proj_kernel<<<(N_NODES + 63) / 64, 256, 0, stream>>>(
      x, W_in, b_in, W_lin, W_src, W_dst, ad, as_, v);
  edge_kernel<<<N_EDGES / 64, 256, 0, stream>>>(
      ei, pos, Wp1, bp1, Wp2, bp2, Wa1, ba1, Wa2, ba2, ad, as_, v, num, den);
  out_kernel<<<(N_NODES + 63) / 64, 256, 0, stream>>>(num, den, W_out, b_out, out);
}

// Round 3
// 1591.509 us; speedup vs baseline: 6.8804x; 6.8804x over previous
//
#include <hip/hip_runtime.h>

#define N_NODES 100000
#define N_EDGES 1600000
#define PITCH 68  // floats per LDS row: 16B-aligned, conflict-free b128 pattern

// wave-uniform channel-chunk base (wave w owns channels [16w, 16w+16))
__device__ __forceinline__ int wave_c0() {
  return __builtin_amdgcn_readfirstlane((int)((threadIdx.x >> 6) << 4));
}

// acc[j] = (BIAS? bias[c0+j]:0) + sum_k Alds[lane][k] * W[k*64 + c0 + j], opt relu.
// W/bias indices are wave-uniform -> compiler emits scalar loads, FMA uses SGPR src.
template<bool RELU, bool BIAS>
__device__ __forceinline__ void wave_gemm16(const float* Alds, int lane, int c0,
                                            const float* __restrict__ W,
                                            const float* __restrict__ bias,
                                            float acc[16]) {
#pragma unroll
  for (int j = 0; j < 16; ++j) acc[j] = BIAS ? bias[c0 + j] : 0.0f;
  const float* arow = Alds + lane * PITCH;
#pragma unroll
  for (int k = 0; k < 64; k += 4) {
    const float4 a4 = *reinterpret_cast<const float4*>(arow + k);
    const float av[4] = {a4.x, a4.y, a4.z, a4.w};
#pragma unroll
    for (int kk = 0; kk < 4; ++kk) {
#pragma unroll
      for (int j = 0; j < 16; ++j)
        acc[j] = fmaf(av[kk], W[(k + kk) * 64 + c0 + j], acc[j]);
    }
  }
  if (RELU) {
#pragma unroll
    for (int j = 0; j < 16; ++j) acc[j] = fmaxf(acc[j], 0.0f);
  }
}

__device__ __forceinline__ void store4x4(float* dst, const float a[16]) {
#pragma unroll
  for (int q = 0; q < 4; ++q)
    *reinterpret_cast<float4*>(dst + q * 4) =
        make_float4(a[q * 4], a[q * 4 + 1], a[q * 4 + 2], a[q * 4 + 3]);
}

// ---- CSR build: histogram -> exclusive scan -> scatter (dst-sorted order) ----
__global__ __launch_bounds__(256) void hist_kernel(const int* __restrict__ ei,
                                                   int* __restrict__ counts) {
  int e = blockIdx.x * 256 + threadIdx.x;
  if (e < N_EDGES) atomicAdd(&counts[ei[N_EDGES + e]], 1);
}

// single block, 1024 threads: chunked exclusive scan of counts[0..N) -> cursor[0..N]
__global__ __launch_bounds__(1024) void scan_kernel(const int* __restrict__ counts,
                                                    int* __restrict__ cursor) {
  __shared__ int wsum[16];
  __shared__ int carry_s;
  const int tid = threadIdx.x, lane = tid & 63, wid = tid >> 6;
  if (tid == 0) carry_s = 0;
  __syncthreads();
  for (int base = 0; base < N_NODES + 1; base += 1024) {
    int idx = base + tid;
    int val = (idx < N_NODES) ? counts[idx] : 0;
    int x = val;
#pragma unroll
    for (int o = 1; o < 64; o <<= 1) {
      int y = __shfl_up(x, o);
      if (lane >= o) x += y;
    }
    if (lane == 63) wsum[wid] = x;
    __syncthreads();
    if (wid == 0) {
      int s = (lane < 16) ? wsum[lane] : 0;
#pragma unroll
      for (int o = 1; o < 16; o <<= 1) {
        int y = __shfl_up(s, o);
        if (lane >= o) s += y;
      }
      if (lane < 16) wsum[lane] = s;
    }
    __syncthreads();
    int carry = carry_s;
    int woff = (wid > 0) ? wsum[wid - 1] : 0;
    int incl = carry + woff + x;
    if (idx <= N_NODES) cursor[idx] = incl - val;  // exclusive
    __syncthreads();  // everyone read carry_s before update
    if (tid == 1023) carry_s = incl;
    __syncthreads();
  }
}

__global__ __launch_bounds__(256) void scatter_kernel(const int* __restrict__ ei,
                                                      int* __restrict__ cursor,
                                                      int2* __restrict__ order2) {
  int e = blockIdx.x * 256 + threadIdx.x;
  if (e < N_EDGES) {
    int s = ei[e];
    int d = ei[N_EDGES + e];
    int p = atomicAdd(&cursor[d], 1);
    order2[p] = make_int2(s, d);
  }
}

// ---- Kernel A: h = relu(x@W_in+b_in); ad=h@W_dst; as=h@W_src; v=h@W_lin ----
__global__ __launch_bounds__(256) void node_proj_kernel(
    const float* __restrict__ x, const float* __restrict__ W_in,
    const float* __restrict__ b_in, const float* __restrict__ W_lin,
    const float* __restrict__ W_src, const float* __restrict__ W_dst,
    float* __restrict__ ad, float* __restrict__ as_, float* __restrict__ v) {
  __shared__ __align__(16) float A[64 * PITCH];
  const int tid = threadIdx.x, lane = tid & 63, c0 = wave_c0();
  const int n0 = blockIdx.x * 64;
#pragma unroll
  for (int i = 0; i < 4; ++i) {
    int idx4 = tid + i * 256;  // 0..1023 float4s
    int e = idx4 >> 4, k4 = (idx4 & 15) * 4;
    int n = n0 + e;
    float4 val = make_float4(0.f, 0.f, 0.f, 0.f);
    if (n < N_NODES) val = *reinterpret_cast<const float4*>(x + (size_t)n * 64 + k4);
    *reinterpret_cast<float4*>(&A[e * PITCH + k4]) = val;
  }
  __syncthreads();
  float h[16];
  wave_gemm16<true, true>(A, lane, c0, W_in, b_in, h);
  __syncthreads();
  store4x4(&A[lane * PITCH + c0], h);
  __syncthreads();
  float o1[16], o2[16], o3[16];
  wave_gemm16<false, false>(A, lane, c0, W_dst, nullptr, o1);
  wave_gemm16<false, false>(A, lane, c0, W_src, nullptr, o2);
  wave_gemm16<false, false>(A, lane, c0, W_lin, nullptr, o3);
  const int n = n0 + lane;
  if (n < N_NODES) {
    store4x4(ad + (size_t)n * 64 + c0, o1);
    store4x4(as_ + (size_t)n * 64 + c0, o2);
    store4x4(v + (size_t)n * 64 + c0, o3);
  }
}

// ---- Kernel B: per-edge MLPs (dst-sorted) + exp + segmented-reduce scatter ----
__global__ __launch_bounds__(256) void edge_kernel(
    const int2* __restrict__ order2, const float* __restrict__ pos,
    const float* __restrict__ Wp1, const float* __restrict__ bp1,
    const float* __restrict__ Wp2, const float* __restrict__ bp2,
    const float* __restrict__ Wa1, const float* __restrict__ ba1,
    const float* __restrict__ Wa2, const float* __restrict__ ba2,
    const float* __restrict__ ad, const float* __restrict__ as_,
    const float* __restrict__ v, float* __restrict__ num,
    float* __restrict__ den) {
  __shared__ __align__(16) float A[64 * PITCH];
  const int tid = threadIdx.x, lane = tid & 63, c0 = wave_c0();
  const int i = blockIdx.x * 64 + lane;  // sorted edge slot (E % 64 == 0)
  const int2 sd = order2[i];
  const int s = sd.x, d = sd.y;
  const float2 pd = reinterpret_cast<const float2*>(pos)[d];
  const float2 ps = reinterpret_cast<const float2*>(pos)[s];
  const float dx = pd.x - ps.x, dy = pd.y - ps.y;
  // hp chunk (pos-MLP layer 1) -> LDS
#pragma unroll
  for (int q = 0; q < 4; ++q) {
    float t4[4];
#pragma unroll
    for (int u = 0; u < 4; ++u) {
      int hh = c0 + q * 4 + u;
      t4[u] = fmaxf(fmaf(dx, Wp1[hh], fmaf(dy, Wp1[64 + hh], bp1[hh])), 0.0f);
    }
    *reinterpret_cast<float4*>(&A[lane * PITCH + c0 + q * 4]) =
        make_float4(t4[0], t4[1], t4[2], t4[3]);
  }
  __syncthreads();
  float delta[16];
  wave_gemm16<true, true>(A, lane, c0, Wp2, bp2, delta);
  __syncthreads();
  // a_in = ad[d] - as[s] + delta -> LDS
#pragma unroll
  for (int q = 0; q < 4; ++q) {
    float4 a4 = *reinterpret_cast<const float4*>(ad + (size_t)d * 64 + c0 + q * 4);
    float4 b4 = *reinterpret_cast<const float4*>(as_ + (size_t)s * 64 + c0 + q * 4);
    float4 r;
    r.x = a4.x - b4.x + delta[q * 4 + 0];
    r.y = a4.y - b4.y + delta[q * 4 + 1];
    r.z = a4.z - b4.z + delta[q * 4 + 2];
    r.w = a4.w - b4.w + delta[q * 4 + 3];
    *reinterpret_cast<float4*>(&A[lane * PITCH + c0 + q * 4]) = r;
  }
  __syncthreads();
  float ha[16];
  wave_gemm16<true, true>(A, lane, c0, Wa1, ba1, ha);
  __syncthreads();
  store4x4(&A[lane * PITCH + c0], ha);
  __syncthreads();
  float aat[16];
  wave_gemm16<true, true>(A, lane, c0, Wa2, ba2, aat);
  // epilogue: ex = exp(a) (amax skipped: a in [0,~7], fp32-safe; softmax invariant)
  float vals[32];  // [0..15]=ex*(v+delta), [16..31]=ex
#pragma unroll
  for (int q = 0; q < 4; ++q) {
    float4 v4 = *reinterpret_cast<const float4*>(v + (size_t)s * 64 + c0 + q * 4);
    const float vv[4] = {v4.x, v4.y, v4.z, v4.w};
#pragma unroll
    for (int u = 0; u < 4; ++u) {
      int j = q * 4 + u;
      float ex = __expf(aat[j]);
      vals[j] = ex * (vv[u] + delta[j]);
      vals[16 + j] = ex;
    }
  }
  // wave-level segmented reduction over contiguous equal-d runs
  const int dprev = __shfl_up(d, 1);
  const int dnext = __shfl_down(d, 1);
  const bool head = (lane == 0) || (d != dprev);
  const bool tail = (lane == 63) || (d != dnext);
  const unsigned long long hb = __ballot(head);
  const unsigned long long maskle =
      (lane == 63) ? ~0ull : ((1ull << (lane + 1)) - 1ull);
  const int myhead = 63 - __clzll(hb & maskle);
#pragma unroll
  for (int o = 1; o < 64; o <<= 1) {
    const bool c = (lane - o) >= myhead;  // false when lane < o
#pragma unroll
    for (int t = 0; t < 32; ++t) {
      float y = __shfl_up(vals[t], o);
      if (c) vals[t] += y;
    }
  }
  if (tail) {
#pragma unroll
    for (int u = 0; u < 16; ++u)
      atomicAdd(&num[(size_t)d * 64 + c0 + u], vals[u]);
#pragma unroll
    for (int u = 0; u < 16; ++u)
      atomicAdd(&den[(size_t)d * 64 + c0 + u], vals[16 + u]);
  }
}

// ---- Kernel C: out = relu((num/(den+1e-16)) @ W_out + b_out) ----
__global__ __launch_bounds__(256) void out_kernel(
    const float* __restrict__ num, const float* __restrict__ den,
    const float* __restrict__ W_out, const float* __restrict__ b_out,
    float* __restrict__ out) {
  __shared__ __align__(16) float A[64 * PITCH];
  const int tid = threadIdx.x, lane = tid & 63, c0 = wave_c0();
  const int n0 = blockIdx.x * 64;
#pragma unroll
  for (int i = 0; i < 4; ++i) {
    int idx4 = tid + i * 256;
    int e = idx4 >> 4, k4 = (idx4 & 15) * 4;
    int n = n0 + e;
    float4 val = make_float4(0.f, 0.f, 0.f, 0.f);
    if (n < N_NODES) {
      float4 nu = *reinterpret_cast<const float4*>(num + (size_t)n * 64 + k4);
      float4 de = *reinterpret_cast<const float4*>(den + (size_t)n * 64 + k4);
      val.x = nu.x / (de.x + 1e-16f);
      val.y = nu.y / (de.y + 1e-16f);
      val.z = nu.z / (de.z + 1e-16f);
      val.w = nu.w / (de.w + 1e-16f);
    }
    *reinterpret_cast<float4*>(&A[e * PITCH + k4]) = val;
  }
  __syncthreads();
  float o[16];
  wave_gemm16<true, true>(A, lane, c0, W_out, b_out, o);
  const int n = n0 + lane;
  if (n < N_NODES) store4x4(out + (size_t)n * 64 + c0, o);
}

extern "C" void kernel_launch(void* const* d_in, const int* in_sizes, int n_in,
                              void* d_out, int out_size, void* d_ws,
                              size_t ws_size, hipStream_t stream) {
  const float* x     = (const float*)d_in[0];
  const float* pos   = (const float*)d_in[1];
  const int*   ei    = (const int*)d_in[2];
  const float* W_in  = (const float*)d_in[3];
  const float* b_in  = (const float*)d_in[4];
  const float* W_lin = (const float*)d_in[5];
  const float* W_src = (const float*)d_in[6];
  const float* W_dst = (const float*)d_in[7];
  const float* Wp1   = (const float*)d_in[8];
  const float* bp1   = (const float*)d_in[9];
  const float* Wp2   = (const float*)d_in[10];
  const float* bp2   = (const float*)d_in[11];
  const float* Wa1   = (const float*)d_in[12];
  const float* ba1   = (const float*)d_in[13];
  const float* Wa2   = (const float*)d_in[14];
  const float* ba2   = (const float*)d_in[15];
  const float* W_out = (const float*)d_in[16];
  const float* b_out = (const float*)d_in[17];
  float* out = (float*)d_out;

  float* ws = (float*)d_ws;
  const size_t NC = (size_t)N_NODES * 64;
  float* ad    = ws;
  float* as_   = ws + NC;
  float* v     = ws + 2 * NC;
  float* num   = ws + 3 * NC;
  float* den   = ws + 4 * NC;
  int*   counts = (int*)(ws + 5 * NC);            // N_NODES ints
  int*   cursor = counts + N_NODES;               // N_NODES+1 ints
  int2*  order2 = (int2*)(cursor + N_NODES + 2);  // N_EDGES int2 (8B aligned)

  hipMemsetAsync(num, 0, 2 * NC * sizeof(float), stream);    // num+den
  hipMemsetAsync(counts, 0, N_NODES * sizeof(int), stream);  // histogram

  hist_kernel<<<(N_EDGES + 255) / 256, 256, 0, stream>>>(ei, counts);
  scan_kernel<<<1, 1024, 0, stream>>>(counts, cursor);
  scatter_kernel<<<(N_EDGES + 255) / 256, 256, 0, stream>>>(ei, cursor, order2);

  node_proj_kernel<<<(N_NODES + 63) / 64, 256, 0, stream>>>(
      x, W_in, b_in, W_lin, W_src, W_dst, ad, as_, v);
  edge_kernel<<<N_EDGES / 64, 256, 0, stream>>>(
      order2, pos, Wp1, bp1, Wp2, bp2, Wa1, ba1, Wa2, ba2, ad, as_, v, num, den);
  out_kernel<<<(N_NODES + 63) / 64, 256, 0, stream>>>(num, den, W_out, b_out, out);
}

// Round 4
// 1568.919 us; speedup vs baseline: 6.9794x; 1.0144x over previous
//
#include <hip/hip_runtime.h>

#define N_NODES 100000
#define N_EDGES 1600000
#define PITCH 68  // fp32 LDS pitch: 272B = 17 quads == 1 mod 8 -> conflict-free b128
#define PITCHH 72 // f16 LDS pitch: 144B = 9 quads == 1 mod 8 -> conflict-free b128

typedef _Float16 half8 __attribute__((ext_vector_type(8)));
typedef float f32x4 __attribute__((ext_vector_type(4)));

// wave-uniform channel-chunk base (wave w owns channels [16w, 16w+16))
__device__ __forceinline__ int wave_c0() {
  return __builtin_amdgcn_readfirstlane((int)((threadIdx.x >> 6) << 4));
}

// fp32 wave GEMM (kept for node/out kernels)
template<bool RELU, bool BIAS>
__device__ __forceinline__ void wave_gemm16(const float* Alds, int lane, int c0,
                                            const float* __restrict__ W,
                                            const float* __restrict__ bias,
                                            float acc[16]) {
#pragma unroll
  for (int j = 0; j < 16; ++j) acc[j] = BIAS ? bias[c0 + j] : 0.0f;
  const float* arow = Alds + lane * PITCH;
#pragma unroll
  for (int k = 0; k < 64; k += 4) {
    const float4 a4 = *reinterpret_cast<const float4*>(arow + k);
    const float av[4] = {a4.x, a4.y, a4.z, a4.w};
#pragma unroll
    for (int kk = 0; kk < 4; ++kk) {
#pragma unroll
      for (int j = 0; j < 16; ++j)
        acc[j] = fmaf(av[kk], W[(k + kk) * 64 + c0 + j], acc[j]);
    }
  }
  if (RELU) {
#pragma unroll
    for (int j = 0; j < 16; ++j) acc[j] = fmaxf(acc[j], 0.0f);
  }
}

__device__ __forceinline__ void store4x4(float* dst, const float a[16]) {
#pragma unroll
  for (int q = 0; q < 4; ++q)
    *reinterpret_cast<float4*>(dst + q * 4) =
        make_float4(a[q * 4], a[q * 4 + 1], a[q * 4 + 2], a[q * 4 + 3]);
}

// ---- weight prep: wt[m][j][k] = (f16)W_m[k][j]  (transposed, fp16) ----
__global__ __launch_bounds__(256) void wconv_kernel(const float* __restrict__ Wp2,
                                                    const float* __restrict__ Wa1,
                                                    const float* __restrict__ Wa2,
                                                    _Float16* __restrict__ wt) {
  int t = blockIdx.x * 256 + threadIdx.x;  // 0..12287
  if (t >= 3 * 4096) return;
  int m = t >> 12, idx = t & 4095;
  int j = idx >> 6, k = idx & 63;
  const float* W = (m == 0) ? Wp2 : ((m == 1) ? Wa1 : Wa2);
  wt[m * 4096 + j * 64 + k] = (_Float16)W[k * 64 + j];
}

// ---- CSR build: histogram -> exclusive scan -> scatter (dst-sorted order) ----
__global__ __launch_bounds__(256) void hist_kernel(const int* __restrict__ ei,
                                                   int* __restrict__ counts) {
  int e = blockIdx.x * 256 + threadIdx.x;
  if (e < N_EDGES) atomicAdd(&counts[ei[N_EDGES + e]], 1);
}

__global__ __launch_bounds__(1024) void scan_kernel(const int* __restrict__ counts,
                                                    int* __restrict__ cursor) {
  __shared__ int wsum[16];
  __shared__ int carry_s;
  const int tid = threadIdx.x, lane = tid & 63, wid = tid >> 6;
  if (tid == 0) carry_s = 0;
  __syncthreads();
  for (int base = 0; base < N_NODES + 1; base += 1024) {
    int idx = base + tid;
    int val = (idx < N_NODES) ? counts[idx] : 0;
    int x = val;
#pragma unroll
    for (int o = 1; o < 64; o <<= 1) {
      int y = __shfl_up(x, o);
      if (lane >= o) x += y;
    }
    if (lane == 63) wsum[wid] = x;
    __syncthreads();
    if (wid == 0) {
      int s = (lane < 16) ? wsum[lane] : 0;
#pragma unroll
      for (int o = 1; o < 16; o <<= 1) {
        int y = __shfl_up(s, o);
        if (lane >= o) s += y;
      }
      if (lane < 16) wsum[lane] = s;
    }
    __syncthreads();
    int carry = carry_s;
    int woff = (wid > 0) ? wsum[wid - 1] : 0;
    int incl = carry + woff + x;
    if (idx <= N_NODES) cursor[idx] = incl - val;  // exclusive
    __syncthreads();
    if (tid == 1023) carry_s = incl;
    __syncthreads();
  }
}

__global__ __launch_bounds__(256) void scatter_kernel(const int* __restrict__ ei,
                                                      int* __restrict__ cursor,
                                                      int2* __restrict__ order2) {
  int e = blockIdx.x * 256 + threadIdx.x;
  if (e < N_EDGES) {
    int s = ei[e];
    int d = ei[N_EDGES + e];
    int p = atomicAdd(&cursor[d], 1);
    order2[p] = make_int2(s, d);
  }
}

// ---- Kernel A: h = relu(x@W_in+b_in); ad=h@W_dst; as=h@W_src; v=h@W_lin ----
__global__ __launch_bounds__(256) void node_proj_kernel(
    const float* __restrict__ x, const float* __restrict__ W_in,
    const float* __restrict__ b_in, const float* __restrict__ W_lin,
    const float* __restrict__ W_src, const float* __restrict__ W_dst,
    float* __restrict__ ad, float* __restrict__ as_, float* __restrict__ v) {
  __shared__ __align__(16) float A[64 * PITCH];
  const int tid = threadIdx.x, lane = tid & 63, c0 = wave_c0();
  const int n0 = blockIdx.x * 64;
#pragma unroll
  for (int i = 0; i < 4; ++i) {
    int idx4 = tid + i * 256;
    int e = idx4 >> 4, k4 = (idx4 & 15) * 4;
    int n = n0 + e;
    float4 val = make_float4(0.f, 0.f, 0.f, 0.f);
    if (n < N_NODES) val = *reinterpret_cast<const float4*>(x + (size_t)n * 64 + k4);
    *reinterpret_cast<float4*>(&A[e * PITCH + k4]) = val;
  }
  __syncthreads();
  float h[16];
  wave_gemm16<true, true>(A, lane, c0, W_in, b_in, h);
  __syncthreads();
  store4x4(&A[lane * PITCH + c0], h);
  __syncthreads();
  float o1[16], o2[16], o3[16];
  wave_gemm16<false, false>(A, lane, c0, W_dst, nullptr, o1);
  wave_gemm16<false, false>(A, lane, c0, W_src, nullptr, o2);
  wave_gemm16<false, false>(A, lane, c0, W_lin, nullptr, o3);
  const int n = n0 + lane;
  if (n < N_NODES) {
    store4x4(ad + (size_t)n * 64 + c0, o1);
    store4x4(as_ + (size_t)n * 64 + c0, o2);
    store4x4(v + (size_t)n * 64 + c0, o3);
  }
}

// MFMA helper: D[16w..16w+16)[64] = A(rows 16w..,k=0..63) @ Wt^T + bias
// A-frag (16x16x32): row = lane%16, k = 8*(lane/16)+e.  B-frag: col = lane%16,
// k = 8*(lane/16)+e (Wt stored [col][k]).  D: row = 4*(lane>>4)+r, col = lane&15 (+16t).
__device__ __forceinline__ void mfma3(const _Float16* aL, int w, int g, int a,
                                      const _Float16* __restrict__ Wt,
                                      const float* __restrict__ bias,
                                      f32x4 acc[4]) {
  const half8 A0 = *reinterpret_cast<const half8*>(aL + (16 * w + a) * PITCHH + 8 * g);
  const half8 A1 = *reinterpret_cast<const half8*>(aL + (16 * w + a) * PITCHH + 32 + 8 * g);
#pragma unroll
  for (int t = 0; t < 4; ++t) {
    const half8 B0 = *reinterpret_cast<const half8*>(Wt + (16 * t + a) * 64 + 8 * g);
    const half8 B1 = *reinterpret_cast<const half8*>(Wt + (16 * t + a) * 64 + 32 + 8 * g);
    const float bv = bias[16 * t + a];
    f32x4 c = {bv, bv, bv, bv};
    c = __builtin_amdgcn_mfma_f32_16x16x32_f16(A0, B0, c, 0, 0, 0);
    c = __builtin_amdgcn_mfma_f32_16x16x32_f16(A1, B1, c, 0, 0, 0);
    acc[t] = c;
  }
}

// ---- Kernel B: per-edge MLPs via MFMA (dst-sorted) + segmented-reduce scatter ----
__global__ __launch_bounds__(256) void edge_kernel(
    const int2* __restrict__ order2, const float* __restrict__ pos,
    const float* __restrict__ Wp1, const float* __restrict__ bp1,
    const _Float16* __restrict__ wt, const float* __restrict__ bp2,
    const float* __restrict__ ba1, const float* __restrict__ ba2,
    const float* __restrict__ ad, const float* __restrict__ as_,
    const float* __restrict__ v, float* __restrict__ num,
    float* __restrict__ den) {
  __shared__ _Float16 s_act[64 * PITCHH];    // hp, then ha   (wave-private rows)
  __shared__ _Float16 s_delta[64 * PITCHH];  // relu'd delta  (read at epilogue)
  __shared__ __align__(16) float s_ex[64 * PITCH];  // a_in (f16) then ex (f32)
  __shared__ int s_sd[128];
  const int tid = threadIdx.x, lane = tid & 63, w = tid >> 6;
  const int g = lane >> 4, a = lane & 15, c0 = w * 16;
  const int i = blockIdx.x * 64 + lane;  // sorted edge slot (E % 64 == 0)
  const int2 sd = order2[i];
  const int s = sd.x, d = sd.y;
  if (tid < 64) { s_sd[2 * tid] = s; s_sd[2 * tid + 1] = d; }
  // stage0: hp = relu(dpos@Wp1+bp1), lane=edge, channel-chunk c0
  {
    const float2 pd = reinterpret_cast<const float2*>(pos)[d];
    const float2 ps = reinterpret_cast<const float2*>(pos)[s];
    const float dx = pd.x - ps.x, dy = pd.y - ps.y;
    half8 h0, h1;
#pragma unroll
    for (int u = 0; u < 8; ++u) {
      int j0 = c0 + u, j1 = c0 + 8 + u;
      h0[u] = (_Float16)fmaxf(fmaf(dx, Wp1[j0], fmaf(dy, Wp1[64 + j0], bp1[j0])), 0.f);
      h1[u] = (_Float16)fmaxf(fmaf(dx, Wp1[j1], fmaf(dy, Wp1[64 + j1], bp1[j1])), 0.f);
    }
    *reinterpret_cast<half8*>(&s_act[lane * PITCHH + c0]) = h0;
    *reinterpret_cast<half8*>(&s_act[lane * PITCHH + c0 + 8]) = h1;
  }
  __syncthreads();
  f32x4 acc[4];
  // GEMM1: delta = relu(hp@Wp2+bp2); keep relu'd delta in regs, store f16 copy
  mfma3(s_act, w, g, a, wt, bp2, acc);
#pragma unroll
  for (int t = 0; t < 4; ++t)
#pragma unroll
    for (int r = 0; r < 4; ++r) {
      float x = fmaxf(acc[t][r], 0.f);
      acc[t][r] = x;
      s_delta[(16 * w + 4 * g + r) * PITCHH + 16 * t + a] = (_Float16)x;
    }
  // a_in = ad[d] - as[s] + delta  -> f16 into s_ex region (pitch PITCHH)
  {
    _Float16* s_ain = reinterpret_cast<_Float16*>(s_ex);
#pragma unroll
    for (int r = 0; r < 4; ++r) {
      const int e = 16 * w + 4 * g + r;
      const int se = s_sd[2 * e], de = s_sd[2 * e + 1];
#pragma unroll
      for (int t = 0; t < 4; ++t) {
        const int c = 16 * t + a;
        const float ain = ad[(size_t)de * 64 + c] - as_[(size_t)se * 64 + c] + acc[t][r];
        s_ain[e * PITCHH + c] = (_Float16)ain;
      }
    }
  }
  // GEMM2: ha = relu(a_in@Wa1+ba1) -> s_act (rows wave-private)
  mfma3(reinterpret_cast<_Float16*>(s_ex), w, g, a, wt + 4096, ba1, acc);
#pragma unroll
  for (int t = 0; t < 4; ++t)
#pragma unroll
    for (int r = 0; r < 4; ++r)
      s_act[(16 * w + 4 * g + r) * PITCHH + 16 * t + a] = (_Float16)fmaxf(acc[t][r], 0.f);
  __syncthreads();  // all waves' a_in reads done before s_ex is reused for ex
  // GEMM3: aat = relu(ha@Wa2+ba2); ex = exp(aat) -> s_ex fp32
  mfma3(s_act, w, g, a, wt + 2 * 4096, ba2, acc);
#pragma unroll
  for (int t = 0; t < 4; ++t)
#pragma unroll
    for (int r = 0; r < 4; ++r)
      s_ex[(16 * w + 4 * g + r) * PITCH + 16 * t + a] = __expf(fmaxf(acc[t][r], 0.f));
  __syncthreads();
  // epilogue (lane=edge, channels c0..c0+15): vals -> segmented scan -> atomics
  const half8 dl0 = *reinterpret_cast<const half8*>(&s_delta[lane * PITCHH + c0]);
  const half8 dl1 = *reinterpret_cast<const half8*>(&s_delta[lane * PITCHH + c0 + 8]);
  float vals[32];  // [0..15]=ex*(v+delta), [16..31]=ex
#pragma unroll
  for (int q = 0; q < 4; ++q) {
    const float4 v4 = *reinterpret_cast<const float4*>(v + (size_t)s * 64 + c0 + q * 4);
    const float4 e4 = *reinterpret_cast<const float4*>(&s_ex[lane * PITCH + c0 + q * 4]);
    const float vv[4] = {v4.x, v4.y, v4.z, v4.w};
    const float ee[4] = {e4.x, e4.y, e4.z, e4.w};
#pragma unroll
    for (int u = 0; u < 4; ++u) {
      const int j = q * 4 + u;
      const float dj = (float)((j < 8) ? dl0[j] : dl1[j - 8]);
      vals[j] = ee[u] * (vv[u] + dj);
      vals[16 + j] = ee[u];
    }
  }
  // wave-level segmented reduction over contiguous equal-d runs
  const int dprev = __shfl_up(d, 1);
  const int dnext = __shfl_down(d, 1);
  const bool head = (lane == 0) || (d != dprev);
  const bool tail = (lane == 63) || (d != dnext);
  const unsigned long long hb = __ballot(head);
  const unsigned long long maskle =
      (lane == 63) ? ~0ull : ((1ull << (lane + 1)) - 1ull);
  const int myhead = 63 - __clzll(hb & maskle);
#pragma unroll
  for (int o = 1; o < 64; o <<= 1) {
    const bool c = (lane - o) >= myhead;
#pragma unroll
    for (int t = 0; t < 32; ++t) {
      float y = __shfl_up(vals[t], o);
      if (c) vals[t] += y;
    }
  }
  if (tail) {
#pragma unroll
    for (int u = 0; u < 16; ++u)
      atomicAdd(&num[(size_t)d * 64 + c0 + u], vals[u]);
#pragma unroll
    for (int u = 0; u < 16; ++u)
      atomicAdd(&den[(size_t)d * 64 + c0 + u], vals[16 + u]);
  }
}

// ---- Kernel C: out = relu((num/(den+1e-16)) @ W_out + b_out) ----
__global__ __launch_bounds__(256) void out_kernel(
    const float* __restrict__ num, const float* __restrict__ den,
    const float* __restrict__ W_out, const float* __restrict__ b_out,
    float* __restrict__ out) {
  __shared__ __align__(16) float A[64 * PITCH];
  const int tid = threadIdx.x, lane = tid & 63, c0 = wave_c0();
  const int n0 = blockIdx.x * 64;
#pragma unroll
  for (int i = 0; i < 4; ++i) {
    int idx4 = tid + i * 256;
    int e = idx4 >> 4, k4 = (idx4 & 15) * 4;
    int n = n0 + e;
    float4 val = make_float4(0.f, 0.f, 0.f, 0.f);
    if (n < N_NODES) {
      float4 nu = *reinterpret_cast<const float4*>(num + (size_t)n * 64 + k4);
      float4 de = *reinterpret_cast<const float4*>(den + (size_t)n * 64 + k4);
      val.x = nu.x / (de.x + 1e-16f);
      val.y = nu.y / (de.y + 1e-16f);
      val.z = nu.z / (de.z + 1e-16f);
      val.w = nu.w / (de.w + 1e-16f);
    }
    *reinterpret_cast<float4*>(&A[e * PITCH + k4]) = val;
  }
  __syncthreads();
  float o[16];
  wave_gemm16<true, true>(A, lane, c0, W_out, b_out, o);
  const int n = n0 + lane;
  if (n < N_NODES) store4x4(out + (size_t)n * 64 + c0, o);
}

extern "C" void kernel_launch(void* const* d_in, const int* in_sizes, int n_in,
                              void* d_out, int out_size, void* d_ws,
                              size_t ws_size, hipStream_t stream) {
  const float* x     = (const float*)d_in[0];
  const float* pos   = (const float*)d_in[1];
  const int*   ei    = (const int*)d_in[2];
  const float* W_in  = (const float*)d_in[3];
  const float* b_in  = (const float*)d_in[4];
  const float* W_lin = (const float*)d_in[5];
  const float* W_src = (const float*)d_in[6];
  const float* W_dst = (const float*)d_in[7];
  const float* Wp1   = (const float*)d_in[8];
  const float* bp1   = (const float*)d_in[9];
  const float* Wp2   = (const float*)d_in[10];
  const float* bp2   = (const float*)d_in[11];
  const float* Wa1   = (const float*)d_in[12];
  const float* ba1   = (const float*)d_in[13];
  const float* Wa2   = (const float*)d_in[14];
  const float* ba2   = (const float*)d_in[15];
  const float* W_out = (const float*)d_in[16];
  const float* b_out = (const float*)d_in[17];
  float* out = (float*)d_out;

  float* ws = (float*)d_ws;
  const size_t NC = (size_t)N_NODES * 64;
  float* ad    = ws;
  float* as_   = ws + NC;
  float* v     = ws + 2 * NC;
  float* num   = ws + 3 * NC;
  float* den   = ws + 4 * NC;
  int*   counts = (int*)(ws + 5 * NC);            // N_NODES ints
  int*   cursor = counts + N_NODES;               // N_NODES+1 ints
  int2*  order2 = (int2*)(cursor + N_NODES + 2);  // N_EDGES int2 (16B aligned)
  _Float16* wt  = (_Float16*)(order2 + N_EDGES);  // 3*4096 f16 (16B aligned)

  hipMemsetAsync(num, 0, 2 * NC * sizeof(float), stream);    // num+den
  hipMemsetAsync(counts, 0, N_NODES * sizeof(int), stream);  // histogram

  wconv_kernel<<<48, 256, 0, stream>>>(Wp2, Wa1, Wa2, wt);
  hist_kernel<<<(N_EDGES + 255) / 256, 256, 0, stream>>>(ei, counts);
  scan_kernel<<<1, 1024, 0, stream>>>(counts, cursor);
  scatter_kernel<<<(N_EDGES + 255) / 256, 256, 0, stream>>>(ei, cursor, order2);

  node_proj_kernel<<<(N_NODES + 63) / 64, 256, 0, stream>>>(
      x, W_in, b_in, W_lin, W_src, W_dst, ad, as_, v);
  edge_kernel<<<N_EDGES / 64, 256, 0, stream>>>(
      order2, pos, Wp1, bp1, wt, bp2, ba1, ba2, ad, as_, v, num, den);
  out_kernel<<<(N_NODES + 63) / 64, 256, 0, stream>>>(num, den, W_out, b_out, out);
}

// Round 6
// 1067.822 us; speedup vs baseline: 10.2547x; 1.4693x over previous
//
#include <hip/hip_runtime.h>

#define N_NODES 100000
#define N_EDGES 1600000
#define PITCH 68  // fp32 LDS pitch (node/out kernels)
#define PITCHH 72 // f16 LDS pitch: 144B row = 9 quads == 1 mod 8

typedef _Float16 half8 __attribute__((ext_vector_type(8)));
typedef float f32x4 __attribute__((ext_vector_type(4)));

__device__ __forceinline__ int wave_c0() {
  return __builtin_amdgcn_readfirstlane((int)((threadIdx.x >> 6) << 4));
}

// fp32 wave GEMM (node/out kernels)
template<bool RELU, bool BIAS>
__device__ __forceinline__ void wave_gemm16(const float* Alds, int lane, int c0,
                                            const float* __restrict__ W,
                                            const float* __restrict__ bias,
                                            float acc[16]) {
#pragma unroll
  for (int j = 0; j < 16; ++j) acc[j] = BIAS ? bias[c0 + j] : 0.0f;
  const float* arow = Alds + lane * PITCH;
#pragma unroll
  for (int k = 0; k < 64; k += 4) {
    const float4 a4 = *reinterpret_cast<const float4*>(arow + k);
    const float av[4] = {a4.x, a4.y, a4.z, a4.w};
#pragma unroll
    for (int kk = 0; kk < 4; ++kk) {
#pragma unroll
      for (int j = 0; j < 16; ++j)
        acc[j] = fmaf(av[kk], W[(k + kk) * 64 + c0 + j], acc[j]);
    }
  }
  if (RELU) {
#pragma unroll
    for (int j = 0; j < 16; ++j) acc[j] = fmaxf(acc[j], 0.0f);
  }
}

__device__ __forceinline__ void store4x4(float* dst, const float a[16]) {
#pragma unroll
  for (int q = 0; q < 4; ++q)
    *reinterpret_cast<float4*>(dst + q * 4) =
        make_float4(a[q * 4], a[q * 4 + 1], a[q * 4 + 2], a[q * 4 + 3]);
}

__device__ __forceinline__ void store16h(_Float16* dst, const float a[16]) {
  half8 h0, h1;
#pragma unroll
  for (int u = 0; u < 8; ++u) {
    h0[u] = (_Float16)a[u];
    h1[u] = (_Float16)a[8 + u];
  }
  *reinterpret_cast<half8*>(dst) = h0;
  *reinterpret_cast<half8*>(dst + 8) = h1;
}

// ---- weight prep: wt[m][j][k] = (f16)W_m[k][j]  (transposed, fp16) ----
__global__ __launch_bounds__(256) void wconv_kernel(const float* __restrict__ Wp2,
                                                    const float* __restrict__ Wa1,
                                                    const float* __restrict__ Wa2,
                                                    _Float16* __restrict__ wt) {
  int t = blockIdx.x * 256 + threadIdx.x;
  if (t >= 3 * 4096) return;
  int m = t >> 12, idx = t & 4095;
  int j = idx >> 6, k = idx & 63;
  const float* W = (m == 0) ? Wp2 : ((m == 1) ? Wa1 : Wa2);
  wt[m * 4096 + j * 64 + k] = (_Float16)W[k * 64 + j];
}

// ---- CSR build: histogram -> exclusive scan -> scatter (dst-sorted order) ----
__global__ __launch_bounds__(256) void hist_kernel(const int* __restrict__ ei,
                                                   int* __restrict__ counts) {
  int e = blockIdx.x * 256 + threadIdx.x;
  if (e < N_EDGES) atomicAdd(&counts[ei[N_EDGES + e]], 1);
}

__global__ __launch_bounds__(1024) void scan_kernel(const int* __restrict__ counts,
                                                    int* __restrict__ cursor) {
  __shared__ int wsum[16];
  __shared__ int carry_s;
  const int tid = threadIdx.x, lane = tid & 63, wid = tid >> 6;
  if (tid == 0) carry_s = 0;
  __syncthreads();
  for (int base = 0; base < N_NODES + 1; base += 1024) {
    int idx = base + tid;
    int val = (idx < N_NODES) ? counts[idx] : 0;
    int x = val;
#pragma unroll
    for (int o = 1; o < 64; o <<= 1) {
      int y = __shfl_up(x, o);
      if (lane >= o) x += y;
    }
    if (lane == 63) wsum[wid] = x;
    __syncthreads();
    if (wid == 0) {
      int s = (lane < 16) ? wsum[lane] : 0;
#pragma unroll
      for (int o = 1; o < 16; o <<= 1) {
        int y = __shfl_up(s, o);
        if (lane >= o) s += y;
      }
      if (lane < 16) wsum[lane] = s;
    }
    __syncthreads();
    int carry = carry_s;
    int woff = (wid > 0) ? wsum[wid - 1] : 0;
    int incl = carry + woff + x;
    if (idx <= N_NODES) cursor[idx] = incl - val;  // exclusive
    __syncthreads();
    if (tid == 1023) carry_s = incl;
    __syncthreads();
  }
}

__global__ __launch_bounds__(256) void scatter_kernel(const int* __restrict__ ei,
                                                      int* __restrict__ cursor,
                                                      int2* __restrict__ order2) {
  int e = blockIdx.x * 256 + threadIdx.x;
  if (e < N_EDGES) {
    int s = ei[e];
    int d = ei[N_EDGES + e];
    int p = atomicAdd(&cursor[d], 1);
    order2[p] = make_int2(s, d);
  }
}

// ---- Kernel A: h = relu(x@W_in+b_in); ad=h@W_dst; as=h@W_src; v=h@W_lin (fp16 out)
__global__ __launch_bounds__(256) void node_proj_kernel(
    const float* __restrict__ x, const float* __restrict__ W_in,
    const float* __restrict__ b_in, const float* __restrict__ W_lin,
    const float* __restrict__ W_src, const float* __restrict__ W_dst,
    _Float16* __restrict__ adh, _Float16* __restrict__ ash,
    _Float16* __restrict__ vh) {
  __shared__ __align__(16) float A[64 * PITCH];
  const int tid = threadIdx.x, lane = tid & 63, c0 = wave_c0();
  const int n0 = blockIdx.x * 64;
#pragma unroll
  for (int i = 0; i < 4; ++i) {
    int idx4 = tid + i * 256;
    int e = idx4 >> 4, k4 = (idx4 & 15) * 4;
    int n = n0 + e;
    float4 val = make_float4(0.f, 0.f, 0.f, 0.f);
    if (n < N_NODES) val = *reinterpret_cast<const float4*>(x + (size_t)n * 64 + k4);
    *reinterpret_cast<float4*>(&A[e * PITCH + k4]) = val;
  }
  __syncthreads();
  float h[16];
  wave_gemm16<true, true>(A, lane, c0, W_in, b_in, h);
  __syncthreads();
  store4x4(&A[lane * PITCH + c0], h);
  __syncthreads();
  float o1[16], o2[16], o3[16];
  wave_gemm16<false, false>(A, lane, c0, W_dst, nullptr, o1);
  wave_gemm16<false, false>(A, lane, c0, W_src, nullptr, o2);
  wave_gemm16<false, false>(A, lane, c0, W_lin, nullptr, o3);
  const int n = n0 + lane;
  if (n < N_NODES) {
    store16h(adh + (size_t)n * 64 + c0, o1);
    store16h(ash + (size_t)n * 64 + c0, o2);
    store16h(vh + (size_t)n * 64 + c0, o3);
  }
}

// MFMA helper: A-frag row = 16w + (lane&15), k = 8*(lane>>4)+e (+32).
// D: row = 16w + 4*(lane>>4)+r, col = 16t + (lane&15).
__device__ __forceinline__ void mfma3(const _Float16* aL, int w, int g, int a,
                                      const _Float16* __restrict__ Wt,
                                      const float* __restrict__ bias,
                                      f32x4 acc[4]) {
  const half8 A0 = *reinterpret_cast<const half8*>(aL + (16 * w + a) * PITCHH + 8 * g);
  const half8 A1 = *reinterpret_cast<const half8*>(aL + (16 * w + a) * PITCHH + 32 + 8 * g);
#pragma unroll
  for (int t = 0; t < 4; ++t) {
    const half8 B0 = *reinterpret_cast<const half8*>(Wt + (16 * t + a) * 64 + 8 * g);
    const half8 B1 = *reinterpret_cast<const half8*>(Wt + (16 * t + a) * 64 + 32 + 8 * g);
    const float bv = bias[16 * t + a];
    f32x4 c = {bv, bv, bv, bv};
    c = __builtin_amdgcn_mfma_f32_16x16x32_f16(A0, B0, c, 0, 0, 0);
    c = __builtin_amdgcn_mfma_f32_16x16x32_f16(A1, B1, c, 0, 0, 0);
    acc[t] = c;
  }
}

// ---- Kernel B: per-edge MLPs via MFMA + seg-reduce; store complete segments ----
__global__ __launch_bounds__(256) void edge_kernel(
    const int2* __restrict__ order2, const float* __restrict__ pos,
    const float* __restrict__ Wp1, const float* __restrict__ bp1,
    const _Float16* __restrict__ wt, const float* __restrict__ bp2,
    const float* __restrict__ ba1, const float* __restrict__ ba2,
    const _Float16* __restrict__ adh, const _Float16* __restrict__ ash,
    const _Float16* __restrict__ vh, float* __restrict__ num,
    float* __restrict__ den) {
  __shared__ _Float16 s_act[64 * PITCHH];    // hp -> a_in -> ha (wave-private rows)
  __shared__ _Float16 s_delta[64 * PITCHH];  // relu'd delta
  __shared__ _Float16 s_v[64 * PITCHH];      // gathered v rows
  __shared__ _Float16 s_ex[64 * PITCHH];     // exp(aat)
  __shared__ int s_sd[128];
  const int tid = threadIdx.x, lane = tid & 63, w = tid >> 6;
  const int g = lane >> 4, a = lane & 15, c0 = w * 16;
  const int i = blockIdx.x * 64 + lane;  // sorted edge slot (E % 64 == 0)
  const int2 sd = order2[i];
  const int s = sd.x, d = sd.y;
  if (tid < 64) { s_sd[2 * tid] = s; s_sd[2 * tid + 1] = d; }
  // boundary probes (for store-vs-atomic decision); same for all 4 waves
  int dm1 = -1, dp1 = -1;
  if (lane == 0 && i > 0) dm1 = ((const int*)order2)[2 * (i - 1) + 1];
  if (lane == 63 && i + 1 < N_EDGES) dp1 = ((const int*)order2)[2 * (i + 1) + 1];
  dm1 = __shfl(dm1, 0);
  // stage0: hp = relu(dpos@Wp1+bp1), lane=edge, this wave's channel chunk
  {
    const float2 pd = reinterpret_cast<const float2*>(pos)[d];
    const float2 ps = reinterpret_cast<const float2*>(pos)[s];
    const float dx = pd.x - ps.x, dy = pd.y - ps.y;
    half8 h0, h1;
#pragma unroll
    for (int u = 0; u < 8; ++u) {
      int j0 = c0 + u, j1 = c0 + 8 + u;
      h0[u] = (_Float16)fmaxf(fmaf(dx, Wp1[j0], fmaf(dy, Wp1[64 + j0], bp1[j0])), 0.f);
      h1[u] = (_Float16)fmaxf(fmaf(dx, Wp1[j1], fmaf(dy, Wp1[64 + j1], bp1[j1])), 0.f);
    }
    *reinterpret_cast<half8*>(&s_act[lane * PITCHH + c0]) = h0;
    *reinterpret_cast<half8*>(&s_act[lane * PITCHH + c0 + 8]) = h1;
  }
  __syncthreads();  // (1) hp columns + s_sd visible
  f32x4 acc[4];
  // GEMM1: delta = relu(hp@Wp2+bp2) -> s_delta (D-frag, wave-private rows)
  mfma3(s_act, w, g, a, wt, bp2, acc);
#pragma unroll
  for (int t = 0; t < 4; ++t)
#pragma unroll
    for (int r = 0; r < 4; ++r)
      s_delta[(16 * w + 4 * g + r) * PITCHH + 16 * t + a] =
          (_Float16)fmaxf(acc[t][r], 0.f);
  // a_in row phase: 4 threads per own-wave row, 32B contiguous fp16 gathers
  {
    const int er = 16 * w + (lane >> 2), p = lane & 3;
    const int se = s_sd[2 * er], de = s_sd[2 * er + 1];
    const half8 ad0 = *reinterpret_cast<const half8*>(adh + (size_t)de * 64 + 16 * p);
    const half8 ad1 = *reinterpret_cast<const half8*>(adh + (size_t)de * 64 + 16 * p + 8);
    const half8 as0 = *reinterpret_cast<const half8*>(ash + (size_t)se * 64 + 16 * p);
    const half8 as1 = *reinterpret_cast<const half8*>(ash + (size_t)se * 64 + 16 * p + 8);
    const half8 dl0 = *reinterpret_cast<const half8*>(&s_delta[er * PITCHH + 16 * p]);
    const half8 dl1 = *reinterpret_cast<const half8*>(&s_delta[er * PITCHH + 16 * p + 8]);
    *reinterpret_cast<half8*>(&s_act[er * PITCHH + 16 * p]) = ad0 - as0 + dl0;
    *reinterpret_cast<half8*>(&s_act[er * PITCHH + 16 * p + 8]) = ad1 - as1 + dl1;
    const half8 v0 = *reinterpret_cast<const half8*>(vh + (size_t)se * 64 + 16 * p);
    const half8 v1 = *reinterpret_cast<const half8*>(vh + (size_t)se * 64 + 16 * p + 8);
    *reinterpret_cast<half8*>(&s_v[er * PITCHH + 16 * p]) = v0;
    *reinterpret_cast<half8*>(&s_v[er * PITCHH + 16 * p + 8]) = v1;
  }
  // GEMM2: ha = relu(a_in@Wa1+ba1) -> s_act (same-wave rows, in-order LDS)
  mfma3(s_act, w, g, a, wt + 4096, ba1, acc);
#pragma unroll
  for (int t = 0; t < 4; ++t)
#pragma unroll
    for (int r = 0; r < 4; ++r)
      s_act[(16 * w + 4 * g + r) * PITCHH + 16 * t + a] =
          (_Float16)fmaxf(acc[t][r], 0.f);
  // GEMM3: aat = relu(ha@Wa2+ba2); ex = exp(aat) -> s_ex fp16
  mfma3(s_act, w, g, a, wt + 2 * 4096, ba2, acc);
#pragma unroll
  for (int t = 0; t < 4; ++t)
#pragma unroll
    for (int r = 0; r < 4; ++r)
      s_ex[(16 * w + 4 * g + r) * PITCHH + 16 * t + a] =
          (_Float16)__expf(fmaxf(acc[t][r], 0.f));
  __syncthreads();  // (2) cross-wave rows of s_ex/s_v/s_delta
  // epilogue (lane=edge, channels c0..c0+15)
  const half8 e0 = *reinterpret_cast<const half8*>(&s_ex[lane * PITCHH + c0]);
  const half8 e1 = *reinterpret_cast<const half8*>(&s_ex[lane * PITCHH + c0 + 8]);
  const half8 dl0 = *reinterpret_cast<const half8*>(&s_delta[lane * PITCHH + c0]);
  const half8 dl1 = *reinterpret_cast<const half8*>(&s_delta[lane * PITCHH + c0 + 8]);
  const half8 vv0 = *reinterpret_cast<const half8*>(&s_v[lane * PITCHH + c0]);
  const half8 vv1 = *reinterpret_cast<const half8*>(&s_v[lane * PITCHH + c0 + 8]);
  float vals[32];  // [0..15]=ex*(v+delta), [16..31]=ex
#pragma unroll
  for (int j = 0; j < 16; ++j) {
    const float ex = (float)((j < 8) ? e0[j] : e1[j - 8]);
    const float dj = (float)((j < 8) ? dl0[j] : dl1[j - 8]);
    const float vj = (float)((j < 8) ? vv0[j] : vv1[j - 8]);
    vals[j] = ex * (vj + dj);
    vals[16 + j] = ex;
  }
  // wave-level segmented inclusive scan over contiguous equal-d runs
  const int dprev = __shfl_up(d, 1);
  const int dnext = __shfl_down(d, 1);
  const bool head = (lane == 0) || (d != dprev);
  const bool tail = (lane == 63) || (d != dnext);
  const unsigned long long hb = __ballot(head);
  const unsigned long long maskle =
      (lane == 63) ? ~0ull : ((1ull << (lane + 1)) - 1ull);
  const int myhead = 63 - __clzll(hb & maskle);
#pragma unroll
  for (int o = 1; o < 64; o <<= 1) {
    const bool c = (lane - o) >= myhead;
#pragma unroll
    for (int t = 0; t < 32; ++t) {
      float y = __shfl_up(vals[t], o);
      if (c) vals[t] += y;
    }
  }
  if (tail) {
    float* np = num + (size_t)d * 64 + c0;
    float* dp = den + (size_t)d * 64 + c0;
    const bool true_start = (myhead > 0) || (dm1 != d);
    const bool true_end = (lane < 63) || (dp1 != d);
    if (true_start && true_end) {
      // complete segment: exclusive writer of this (d, chunk) -> plain stores
#pragma unroll
      for (int q = 0; q < 4; ++q)
        *reinterpret_cast<float4*>(np + 4 * q) =
            make_float4(vals[4 * q], vals[4 * q + 1], vals[4 * q + 2], vals[4 * q + 3]);
#pragma unroll
      for (int q = 0; q < 4; ++q)
        *reinterpret_cast<float4*>(dp + 4 * q) =
            make_float4(vals[16 + 4 * q], vals[17 + 4 * q], vals[18 + 4 * q],
                        vals[19 + 4 * q]);
    } else {
#pragma unroll
      for (int u = 0; u < 16; ++u) atomicAdd(np + u, vals[u]);
#pragma unroll
      for (int u = 0; u < 16; ++u) atomicAdd(dp + u, vals[16 + u]);
    }
  }
}

// ---- Kernel C: out = relu((num/(den+1e-16)) @ W_out + b_out) ----
__global__ __launch_bounds__(256) void out_kernel(
    const float* __restrict__ num, const float* __restrict__ den,
    const float* __restrict__ W_out, const float* __restrict__ b_out,
    float* __restrict__ out) {
  __shared__ __align__(16) float A[64 * PITCH];
  const int tid = threadIdx.x, lane = tid & 63, c0 = wave_c0();
  const int n0 = blockIdx.x * 64;
#pragma unroll
  for (int i = 0; i < 4; ++i) {
    int idx4 = tid + i * 256;
    int e = idx4 >> 4, k4 = (idx4 & 15) * 4;
    int n = n0 + e;
    float4 val = make_float4(0.f, 0.f, 0.f, 0.f);
    if (n < N_NODES) {
      float4 nu = *reinterpret_cast<const float4*>(num + (size_t)n * 64 + k4);
      float4 de = *reinterpret_cast<const float4*>(den + (size_t)n * 64 + k4);
      val.x = nu.x / (de.x + 1e-16f);
      val.y = nu.y / (de.y + 1e-16f);
      val.z = nu.z / (de.z + 1e-16f);
      val.w = nu.w / (de.w + 1e-16f);
    }
    *reinterpret_cast<float4*>(&A[e * PITCH + k4]) = val;
  }
  __syncthreads();
  float o[16];
  wave_gemm16<true, true>(A, lane, c0, W_out, b_out, o);
  const int n = n0 + lane;
  if (n < N_NODES) store4x4(out + (size_t)n * 64 + c0, o);
}

extern "C" void kernel_launch(void* const* d_in, const int* in_sizes, int n_in,
                              void* d_out, int out_size, void* d_ws,
                              size_t ws_size, hipStream_t stream) {
  const float* x     = (const float*)d_in[0];
  const float* pos   = (const float*)d_in[1];
  const int*   ei    = (const int*)d_in[2];
  const float* W_in  = (const float*)d_in[3];
  const float* b_in  = (const float*)d_in[4];
  const float* W_lin = (const float*)d_in[5];
  const float* W_src = (const float*)d_in[6];
  const float* W_dst = (const float*)d_in[7];
  const float* Wp1   = (const float*)d_in[8];
  const float* bp1   = (const float*)d_in[9];
  const float* Wp2   = (const float*)d_in[10];
  const float* bp2   = (const float*)d_in[11];
  const float* Wa1   = (const float*)d_in[12];
  const float* ba1   = (const float*)d_in[13];
  const float* Wa2   = (const float*)d_in[14];
  const float* ba2   = (const float*)d_in[15];
  const float* W_out = (const float*)d_in[16];
  const float* b_out = (const float*)d_in[17];
  float* out = (float*)d_out;

  const size_t NC = (size_t)N_NODES * 64;
  _Float16* adh = (_Float16*)d_ws;           // NC halfs
  _Float16* ash = adh + NC;                  // NC halfs
  _Float16* vh  = ash + NC;                  // NC halfs
  float* num = (float*)(vh + NC);            // NC floats
  float* den = num + NC;                     // NC floats
  int* counts = (int*)(den + NC);            // N_NODES ints
  int* cursor = counts + N_NODES;            // N_NODES+1 ints (+pad to 16B)
  int2* order2 = (int2*)(cursor + N_NODES + 4);  // N_EDGES int2
  _Float16* wt = (_Float16*)(order2 + N_EDGES);  // 3*4096 f16 (16B aligned)

  hipMemsetAsync(num, 0, 2 * NC * sizeof(float), stream);    // num+den
  hipMemsetAsync(counts, 0, N_NODES * sizeof(int), stream);  // histogram

  wconv_kernel<<<48, 256, 0, stream>>>(Wp2, Wa1, Wa2, wt);
  hist_kernel<<<(N_EDGES + 255) / 256, 256, 0, stream>>>(ei, counts);
  scan_kernel<<<1, 1024, 0, stream>>>(counts, cursor);
  scatter_kernel<<<(N_EDGES + 255) / 256, 256, 0, stream>>>(ei, cursor, order2);

  node_proj_kernel<<<(N_NODES + 63) / 64, 256, 0, stream>>>(
      x, W_in, b_in, W_lin, W_src, W_dst, adh, ash, vh);
  edge_kernel<<<N_EDGES / 64, 256, 0, stream>>>(
      order2, pos, Wp1, bp1, wt, bp2, ba1, ba2, adh, ash, vh, num, den);
  out_kernel<<<(N_NODES + 63) / 64, 256, 0, stream>>>(num, den, W_out, b_out, out);
}

// Round 7
// 1027.923 us; speedup vs baseline: 10.6527x; 1.0388x over previous
//
#include <hip/hip_runtime.h>

#define N_NODES 100000
#define N_EDGES 1600000
#define PITCH 68  // fp32 LDS pitch (node/out kernels)
#define PITCHH 72 // f16 LDS pitch: 144B row = 9 quads == 1 mod 8
#define N_SCAN_BLOCKS ((N_NODES + 1023) / 1024)  // 98

typedef _Float16 half8 __attribute__((ext_vector_type(8)));
typedef float f32x4 __attribute__((ext_vector_type(4)));

__device__ __forceinline__ int wave_c0() {
  return __builtin_amdgcn_readfirstlane((int)((threadIdx.x >> 6) << 4));
}

// fp32 wave GEMM (node/out kernels)
template<bool RELU, bool BIAS>
__device__ __forceinline__ void wave_gemm16(const float* Alds, int lane, int c0,
                                            const float* __restrict__ W,
                                            const float* __restrict__ bias,
                                            float acc[16]) {
#pragma unroll
  for (int j = 0; j < 16; ++j) acc[j] = BIAS ? bias[c0 + j] : 0.0f;
  const float* arow = Alds + lane * PITCH;
#pragma unroll
  for (int k = 0; k < 64; k += 4) {
    const float4 a4 = *reinterpret_cast<const float4*>(arow + k);
    const float av[4] = {a4.x, a4.y, a4.z, a4.w};
#pragma unroll
    for (int kk = 0; kk < 4; ++kk) {
#pragma unroll
      for (int j = 0; j < 16; ++j)
        acc[j] = fmaf(av[kk], W[(k + kk) * 64 + c0 + j], acc[j]);
    }
  }
  if (RELU) {
#pragma unroll
    for (int j = 0; j < 16; ++j) acc[j] = fmaxf(acc[j], 0.0f);
  }
}

__device__ __forceinline__ void store4x4(float* dst, const float a[16]) {
#pragma unroll
  for (int q = 0; q < 4; ++q)
    *reinterpret_cast<float4*>(dst + q * 4) =
        make_float4(a[q * 4], a[q * 4 + 1], a[q * 4 + 2], a[q * 4 + 3]);
}

__device__ __forceinline__ void store16h(_Float16* dst, const float a[16]) {
  half8 h0, h1;
#pragma unroll
  for (int u = 0; u < 8; ++u) {
    h0[u] = (_Float16)a[u];
    h1[u] = (_Float16)a[8 + u];
  }
  *reinterpret_cast<half8*>(dst) = h0;
  *reinterpret_cast<half8*>(dst + 8) = h1;
}

// ---- weight prep: wt[m][j][k] = (f16)W_m[k][j]  (transposed, fp16) ----
__global__ __launch_bounds__(256) void wconv_kernel(const float* __restrict__ Wp2,
                                                    const float* __restrict__ Wa1,
                                                    const float* __restrict__ Wa2,
                                                    _Float16* __restrict__ wt) {
  int t = blockIdx.x * 256 + threadIdx.x;
  if (t >= 3 * 4096) return;
  int m = t >> 12, idx = t & 4095;
  int j = idx >> 6, k = idx & 63;
  const float* W = (m == 0) ? Wp2 : ((m == 1) ? Wa1 : Wa2);
  wt[m * 4096 + j * 64 + k] = (_Float16)W[k * 64 + j];
}

// ---- CSR build: histogram -> 3-kernel parallel scan -> scatter ----
__global__ __launch_bounds__(256) void hist_kernel(const int* __restrict__ ei,
                                                   int* __restrict__ counts) {
  int e = blockIdx.x * 256 + threadIdx.x;
  if (e < N_EDGES) atomicAdd(&counts[ei[N_EDGES + e]], 1);
}

// S1: per-block exclusive scan (1024 elems) + block totals
__global__ __launch_bounds__(1024) void scan1_kernel(const int* __restrict__ counts,
                                                     int* __restrict__ pexcl,
                                                     int* __restrict__ btot) {
  __shared__ int wsum[16];
  const int tid = threadIdx.x, lane = tid & 63, wid = tid >> 6;
  const int idx = blockIdx.x * 1024 + tid;
  const int val = (idx < N_NODES) ? counts[idx] : 0;
  int x = val;
#pragma unroll
  for (int o = 1; o < 64; o <<= 1) {
    int y = __shfl_up(x, o);
    if (lane >= o) x += y;
  }
  if (lane == 63) wsum[wid] = x;
  __syncthreads();
  if (wid == 0) {
    int s = (lane < 16) ? wsum[lane] : 0;
#pragma unroll
    for (int o = 1; o < 16; o <<= 1) {
      int y = __shfl_up(s, o);
      if (lane >= o) s += y;
    }
    if (lane < 16) wsum[lane] = s;
  }
  __syncthreads();
  const int woff = (wid > 0) ? wsum[wid - 1] : 0;
  const int incl = woff + x;
  if (idx < N_NODES) pexcl[idx] = incl - val;
  if (tid == 1023) btot[blockIdx.x] = incl;
}

// S2: single wave exclusive-scans the 98 block totals in place
__global__ __launch_bounds__(64) void scan2_kernel(int* __restrict__ btot) {
  const int lane = threadIdx.x;
  int carry = 0;
  for (int base = 0; base < N_SCAN_BLOCKS; base += 64) {
    const int ii = base + lane;
    const int v = (ii < N_SCAN_BLOCKS) ? btot[ii] : 0;
    int x = v;
#pragma unroll
    for (int o = 1; o < 64; o <<= 1) {
      int y = __shfl_up(x, o);
      if (lane >= o) x += y;
    }
    if (ii < N_SCAN_BLOCKS) btot[ii] = carry + x - v;  // exclusive
    carry += __shfl(x, 63);
  }
}

// S3: cursor = per-block exclusive + block offset
__global__ __launch_bounds__(256) void scan3_kernel(const int* __restrict__ pexcl,
                                                    const int* __restrict__ btot,
                                                    int* __restrict__ cursor) {
  const int idx = blockIdx.x * 256 + threadIdx.x;
  if (idx < N_NODES) cursor[idx] = pexcl[idx] + btot[idx >> 10];
}

__global__ __launch_bounds__(256) void scatter_kernel(const int* __restrict__ ei,
                                                      int* __restrict__ cursor,
                                                      int2* __restrict__ order2) {
  int e = blockIdx.x * 256 + threadIdx.x;
  if (e < N_EDGES) {
    int s = ei[e];
    int d = ei[N_EDGES + e];
    int p = atomicAdd(&cursor[d], 1);
    order2[p] = make_int2(s, d);
  }
}

// ---- Kernel A: h = relu(x@W_in+b_in); ad=h@W_dst; as=h@W_src; v=h@W_lin (fp16 out)
__global__ __launch_bounds__(256) void node_proj_kernel(
    const float* __restrict__ x, const float* __restrict__ W_in,
    const float* __restrict__ b_in, const float* __restrict__ W_lin,
    const float* __restrict__ W_src, const float* __restrict__ W_dst,
    _Float16* __restrict__ adh, _Float16* __restrict__ ash,
    _Float16* __restrict__ vh) {
  __shared__ __align__(16) float A[64 * PITCH];
  const int tid = threadIdx.x, lane = tid & 63, c0 = wave_c0();
  const int n0 = blockIdx.x * 64;
#pragma unroll
  for (int i = 0; i < 4; ++i) {
    int idx4 = tid + i * 256;
    int e = idx4 >> 4, k4 = (idx4 & 15) * 4;
    int n = n0 + e;
    float4 val = make_float4(0.f, 0.f, 0.f, 0.f);
    if (n < N_NODES) val = *reinterpret_cast<const float4*>(x + (size_t)n * 64 + k4);
    *reinterpret_cast<float4*>(&A[e * PITCH + k4]) = val;
  }
  __syncthreads();
  float h[16];
  wave_gemm16<true, true>(A, lane, c0, W_in, b_in, h);
  __syncthreads();
  store4x4(&A[lane * PITCH + c0], h);
  __syncthreads();
  float o1[16], o2[16], o3[16];
  wave_gemm16<false, false>(A, lane, c0, W_dst, nullptr, o1);
  wave_gemm16<false, false>(A, lane, c0, W_src, nullptr, o2);
  wave_gemm16<false, false>(A, lane, c0, W_lin, nullptr, o3);
  const int n = n0 + lane;
  if (n < N_NODES) {
    store16h(adh + (size_t)n * 64 + c0, o1);
    store16h(ash + (size_t)n * 64 + c0, o2);
    store16h(vh + (size_t)n * 64 + c0, o3);
  }
}

// MFMA helper: A-frag row = 16w + (lane&15), k = 8*(lane>>4)+e (+32).
// D: row = 16w + 4*(lane>>4)+r, col = 16t + (lane&15).
__device__ __forceinline__ void mfma3(const _Float16* aL, int w, int g, int a,
                                      const _Float16* __restrict__ Wt,
                                      const float* __restrict__ bias,
                                      f32x4 acc[4]) {
  const half8 A0 = *reinterpret_cast<const half8*>(aL + (16 * w + a) * PITCHH + 8 * g);
  const half8 A1 = *reinterpret_cast<const half8*>(aL + (16 * w + a) * PITCHH + 32 + 8 * g);
#pragma unroll
  for (int t = 0; t < 4; ++t) {
    const half8 B0 = *reinterpret_cast<const half8*>(Wt + (16 * t + a) * 64 + 8 * g);
    const half8 B1 = *reinterpret_cast<const half8*>(Wt + (16 * t + a) * 64 + 32 + 8 * g);
    const float bv = bias[16 * t + a];
    f32x4 c = {bv, bv, bv, bv};
    c = __builtin_amdgcn_mfma_f32_16x16x32_f16(A0, B0, c, 0, 0, 0);
    c = __builtin_amdgcn_mfma_f32_16x16x32_f16(A1, B1, c, 0, 0, 0);
    acc[t] = c;
  }
}

// ---- Kernel B: wave-private edge pipeline, 1 barrier, prefetched gathers ----
__global__ __launch_bounds__(256) void edge_kernel(
    const int2* __restrict__ order2, const float* __restrict__ pos,
    const float* __restrict__ Wp1, const float* __restrict__ bp1,
    const _Float16* __restrict__ wt, const float* __restrict__ bp2,
    const float* __restrict__ ba1, const float* __restrict__ ba2,
    const _Float16* __restrict__ adh, const _Float16* __restrict__ ash,
    const _Float16* __restrict__ vh, float* __restrict__ num,
    float* __restrict__ den) {
  __shared__ _Float16 s_act[64 * PITCHH];    // hp -> a_in -> ha -> ex (wave-private rows)
  __shared__ _Float16 s_delta[64 * PITCHH];  // relu'd delta
  __shared__ _Float16 s_v[64 * PITCHH];      // gathered v rows
  const int tid = threadIdx.x, lane = tid & 63, w = tid >> 6;
  const int g = lane >> 4, a = lane & 15, c0 = w * 16;
  const int i = blockIdx.x * 64 + lane;  // sorted edge slot (E % 64 == 0)
  const int2 sd = order2[i];
  const int d = sd.y;                    // epilogue segment key
  // row-phase mapping: 4 threads per own-wave row (row er, quarter p)
  const int er = 16 * w + (lane >> 2);
  const int p = lane & 3;
  const int2 sd2 = order2[blockIdx.x * 64 + er];
  const int s2 = sd2.x, d2 = sd2.y;
  // prefetch node-row gathers NOW; consumed at a_in phase (overlap stage0+GEMM1)
  const _Float16* adr = adh + (size_t)d2 * 64 + 16 * p;
  const _Float16* asr = ash + (size_t)s2 * 64 + 16 * p;
  const _Float16* vr  = vh  + (size_t)s2 * 64 + 16 * p;
  const half8 ad0 = *reinterpret_cast<const half8*>(adr);
  const half8 ad1 = *reinterpret_cast<const half8*>(adr + 8);
  const half8 as0 = *reinterpret_cast<const half8*>(asr);
  const half8 as1 = *reinterpret_cast<const half8*>(asr + 8);
  const half8 v0  = *reinterpret_cast<const half8*>(vr);
  const half8 v1  = *reinterpret_cast<const half8*>(vr + 8);
  // boundary probes (store-vs-atomic decision)
  int dm1 = -1, dp1 = -1;
  if (lane == 0 && i > 0) dm1 = order2[i - 1].y;
  if (lane == 63 && i + 1 < N_EDGES) dp1 = order2[i + 1].y;
  dm1 = __shfl(dm1, 0);
  // stage0: hp(row er, ch 16p..16p+16) = relu(dpos@Wp1+bp1) -- wave-private rows
  {
    const float2 pd = reinterpret_cast<const float2*>(pos)[d2];
    const float2 ps = reinterpret_cast<const float2*>(pos)[s2];
    const float dx = pd.x - ps.x, dy = pd.y - ps.y;
    half8 h0, h1;
#pragma unroll
    for (int u = 0; u < 8; ++u) {
      const int j0 = 16 * p + u, j1 = 16 * p + 8 + u;
      h0[u] = (_Float16)fmaxf(fmaf(dx, Wp1[j0], fmaf(dy, Wp1[64 + j0], bp1[j0])), 0.f);
      h1[u] = (_Float16)fmaxf(fmaf(dx, Wp1[j1], fmaf(dy, Wp1[64 + j1], bp1[j1])), 0.f);
    }
    *reinterpret_cast<half8*>(&s_act[er * PITCHH + 16 * p]) = h0;
    *reinterpret_cast<half8*>(&s_act[er * PITCHH + 16 * p + 8]) = h1;
  }
  f32x4 acc[4];
  // GEMM1: delta = relu(hp@Wp2+bp2)  (own rows only; DS in-order per wave)
  mfma3(s_act, w, g, a, wt, bp2, acc);
#pragma unroll
  for (int t = 0; t < 4; ++t)
#pragma unroll
    for (int r = 0; r < 4; ++r)
      s_delta[(16 * w + 4 * g + r) * PITCHH + 16 * t + a] =
          (_Float16)fmaxf(acc[t][r], 0.f);
  // a_in = ad[d]-as[s]+delta -> s_act (overwrite hp); v -> s_v  (own rows)
  {
    const half8 dl0 = *reinterpret_cast<const half8*>(&s_delta[er * PITCHH + 16 * p]);
    const half8 dl1 = *reinterpret_cast<const half8*>(&s_delta[er * PITCHH + 16 * p + 8]);
    *reinterpret_cast<half8*>(&s_act[er * PITCHH + 16 * p]) = ad0 - as0 + dl0;
    *reinterpret_cast<half8*>(&s_act[er * PITCHH + 16 * p + 8]) = ad1 - as1 + dl1;
    *reinterpret_cast<half8*>(&s_v[er * PITCHH + 16 * p]) = v0;
    *reinterpret_cast<half8*>(&s_v[er * PITCHH + 16 * p + 8]) = v1;
  }
  // GEMM2: ha = relu(a_in@Wa1+ba1) -> s_act (own rows)
  mfma3(s_act, w, g, a, wt + 4096, ba1, acc);
#pragma unroll
  for (int t = 0; t < 4; ++t)
#pragma unroll
    for (int r = 0; r < 4; ++r)
      s_act[(16 * w + 4 * g + r) * PITCHH + 16 * t + a] =
          (_Float16)fmaxf(acc[t][r], 0.f);
  // GEMM3: aat = relu(ha@Wa2+ba2); ex = exp(aat) -> s_act (own rows, over ha)
  mfma3(s_act, w, g, a, wt + 2 * 4096, ba2, acc);
#pragma unroll
  for (int t = 0; t < 4; ++t)
#pragma unroll
    for (int r = 0; r < 4; ++r)
      s_act[(16 * w + 4 * g + r) * PITCHH + 16 * t + a] =
          (_Float16)__expf(fmaxf(acc[t][r], 0.f));
  __syncthreads();  // ONLY barrier: cross-wave rows of s_act(ex)/s_v/s_delta
  // epilogue (lane=edge, channels c0..c0+15)
  const half8 e0 = *reinterpret_cast<const half8*>(&s_act[lane * PITCHH + c0]);
  const half8 e1 = *reinterpret_cast<const half8*>(&s_act[lane * PITCHH + c0 + 8]);
  const half8 dl0 = *reinterpret_cast<const half8*>(&s_delta[lane * PITCHH + c0]);
  const half8 dl1 = *reinterpret_cast<const half8*>(&s_delta[lane * PITCHH + c0 + 8]);
  const half8 vv0 = *reinterpret_cast<const half8*>(&s_v[lane * PITCHH + c0]);
  const half8 vv1 = *reinterpret_cast<const half8*>(&s_v[lane * PITCHH + c0 + 8]);
  float vals[32];  // [0..15]=ex*(v+delta), [16..31]=ex
#pragma unroll
  for (int j = 0; j < 16; ++j) {
    const float ex = (float)((j < 8) ? e0[j] : e1[j - 8]);
    const float dj = (float)((j < 8) ? dl0[j] : dl1[j - 8]);
    const float vj = (float)((j < 8) ? vv0[j] : vv1[j - 8]);
    vals[j] = ex * (vj + dj);
    vals[16 + j] = ex;
  }
  // wave-level segmented inclusive scan over contiguous equal-d runs
  const int dprev = __shfl_up(d, 1);
  const int dnext = __shfl_down(d, 1);
  const bool head = (lane == 0) || (d != dprev);
  const bool tail = (lane == 63) || (d != dnext);
  const unsigned long long hb = __ballot(head);
  const unsigned long long maskle =
      (lane == 63) ? ~0ull : ((1ull << (lane + 1)) - 1ull);
  const int myhead = 63 - __clzll(hb & maskle);
#pragma unroll
  for (int o = 1; o < 64; o <<= 1) {
    const bool c = (lane - o) >= myhead;
#pragma unroll
    for (int t = 0; t < 32; ++t) {
      float y = __shfl_up(vals[t], o);
      if (c) vals[t] += y;
    }
  }
  if (tail) {
    float* np = num + (size_t)d * 64 + c0;
    float* dp = den + (size_t)d * 64 + c0;
    const bool true_start = (myhead > 0) || (dm1 != d);
    const bool true_end = (lane < 63) || (dp1 != d);
    if (true_start && true_end) {
#pragma unroll
      for (int q = 0; q < 4; ++q)
        *reinterpret_cast<float4*>(np + 4 * q) =
            make_float4(vals[4 * q], vals[4 * q + 1], vals[4 * q + 2], vals[4 * q + 3]);
#pragma unroll
      for (int q = 0; q < 4; ++q)
        *reinterpret_cast<float4*>(dp + 4 * q) =
            make_float4(vals[16 + 4 * q], vals[17 + 4 * q], vals[18 + 4 * q],
                        vals[19 + 4 * q]);
    } else {
#pragma unroll
      for (int u = 0; u < 16; ++u) atomicAdd(np + u, vals[u]);
#pragma unroll
      for (int u = 0; u < 16; ++u) atomicAdd(dp + u, vals[16 + u]);
    }
  }
}

// ---- Kernel C: out = relu((num/(den+1e-16)) @ W_out + b_out) ----
__global__ __launch_bounds__(256) void out_kernel(
    const float* __restrict__ num, const float* __restrict__ den,
    const float* __restrict__ W_out, const float* __restrict__ b_out,
    float* __restrict__ out) {
  __shared__ __align__(16) float A[64 * PITCH];
  const int tid = threadIdx.x, lane = tid & 63, c0 = wave_c0();
  const int n0 = blockIdx.x * 64;
#pragma unroll
  for (int i = 0; i < 4; ++i) {
    int idx4 = tid + i * 256;
    int e = idx4 >> 4, k4 = (idx4 & 15) * 4;
    int n = n0 + e;
    float4 val = make_float4(0.f, 0.f, 0.f, 0.f);
    if (n < N_NODES) {
      float4 nu = *reinterpret_cast<const float4*>(num + (size_t)n * 64 + k4);
      float4 de = *reinterpret_cast<const float4*>(den + (size_t)n * 64 + k4);
      val.x = nu.x / (de.x + 1e-16f);
      val.y = nu.y / (de.y + 1e-16f);
      val.z = nu.z / (de.z + 1e-16f);
      val.w = nu.w / (de.w + 1e-16f);
    }
    *reinterpret_cast<float4*>(&A[e * PITCH + k4]) = val;
  }
  __syncthreads();
  float o[16];
  wave_gemm16<true, true>(A, lane, c0, W_out, b_out, o);
  const int n = n0 + lane;
  if (n < N_NODES) store4x4(out + (size_t)n * 64 + c0, o);
}

extern "C" void kernel_launch(void* const* d_in, const int* in_sizes, int n_in,
                              void* d_out, int out_size, void* d_ws,
                              size_t ws_size, hipStream_t stream) {
  const float* x     = (const float*)d_in[0];
  const float* pos   = (const float*)d_in[1];
  const int*   ei    = (const int*)d_in[2];
  const float* W_in  = (const float*)d_in[3];
  const float* b_in  = (const float*)d_in[4];
  const float* W_lin = (const float*)d_in[5];
  const float* W_src = (const float*)d_in[6];
  const float* W_dst = (const float*)d_in[7];
  const float* Wp1   = (const float*)d_in[8];
  const float* bp1   = (const float*)d_in[9];
  const float* Wp2   = (const float*)d_in[10];
  const float* bp2   = (const float*)d_in[11];
  const float* Wa1   = (const float*)d_in[12];
  const float* ba1   = (const float*)d_in[13];
  const float* Wa2   = (const float*)d_in[14];
  const float* ba2   = (const float*)d_in[15];
  const float* W_out = (const float*)d_in[16];
  const float* b_out = (const float*)d_in[17];
  float* out = (float*)d_out;

  const size_t NC = (size_t)N_NODES * 64;
  _Float16* adh = (_Float16*)d_ws;               // NC halfs
  _Float16* ash = adh + NC;                      // NC halfs
  _Float16* vh  = ash + NC;                      // NC halfs
  float* num = (float*)(vh + NC);                // NC floats
  float* den = num + NC;                         // NC floats
  int* counts = (int*)(den + NC);                // N_NODES ints
  int* cursor = counts + N_NODES;                // N_NODES ints
  int* pexcl  = cursor + N_NODES;                // N_NODES ints
  int* btot   = pexcl + N_NODES;                 // 128 ints
  int2* order2 = (int2*)(btot + 128);            // N_EDGES int2 (8B aligned)
  _Float16* wt = (_Float16*)(order2 + N_EDGES);  // 3*4096 f16

  hipMemsetAsync(num, 0, 2 * NC * sizeof(float), stream);    // num+den
  hipMemsetAsync(counts, 0, N_NODES * sizeof(int), stream);  // histogram

  wconv_kernel<<<48, 256, 0, stream>>>(Wp2, Wa1, Wa2, wt);
  hist_kernel<<<(N_EDGES + 255) / 256, 256, 0, stream>>>(ei, counts);
  scan1_kernel<<<N_SCAN_BLOCKS, 1024, 0, stream>>>(counts, pexcl, btot);
  scan2_kernel<<<1, 64, 0, stream>>>(btot);
  scan3_kernel<<<(N_NODES + 255) / 256, 256, 0, stream>>>(pexcl, btot, cursor);
  scatter_kernel<<<(N_EDGES + 255) / 256, 256, 0, stream>>>(ei, cursor, order2);

  node_proj_kernel<<<(N_NODES + 63) / 64, 256, 0, stream>>>(
      x, W_in, b_in, W_lin, W_src, W_dst, adh, ash, vh);
  edge_kernel<<<N_EDGES / 64, 256, 0, stream>>>(
      order2, pos, Wp1, bp1, wt, bp2, ba1, ba2, adh, ash, vh, num, den);
  out_kernel<<<(N_NODES + 63) / 64, 256, 0, stream>>>(num, den, W_out, b_out, out);
}

// Round 8
// 814.761 us; speedup vs baseline: 13.4397x; 1.2616x over previous
//
#include <hip/hip_runtime.h>

#define N_NODES 100000
#define N_EDGES 1600000
#define NB (N_EDGES / 64)  // 25000 edge blocks
#define PITCH 68  // fp32 LDS pitch (node/out kernels)
#define PITCHH 72 // f16 LDS pitch: 144B row = 9 quads == 1 mod 8
#define N_SCAN_BLOCKS ((N_NODES + 1023) / 1024)  // 98

typedef _Float16 half8 __attribute__((ext_vector_type(8)));
typedef float f32x4 __attribute__((ext_vector_type(4)));

__device__ __forceinline__ int wave_c0() {
  return __builtin_amdgcn_readfirstlane((int)((threadIdx.x >> 6) << 4));
}

// fp32 wave GEMM (node/out kernels)
template<bool RELU, bool BIAS>
__device__ __forceinline__ void wave_gemm16(const float* Alds, int lane, int c0,
                                            const float* __restrict__ W,
                                            const float* __restrict__ bias,
                                            float acc[16]) {
#pragma unroll
  for (int j = 0; j < 16; ++j) acc[j] = BIAS ? bias[c0 + j] : 0.0f;
  const float* arow = Alds + lane * PITCH;
#pragma unroll
  for (int k = 0; k < 64; k += 4) {
    const float4 a4 = *reinterpret_cast<const float4*>(arow + k);
    const float av[4] = {a4.x, a4.y, a4.z, a4.w};
#pragma unroll
    for (int kk = 0; kk < 4; ++kk) {
#pragma unroll
      for (int j = 0; j < 16; ++j)
        acc[j] = fmaf(av[kk], W[(k + kk) * 64 + c0 + j], acc[j]);
    }
  }
  if (RELU) {
#pragma unroll
    for (int j = 0; j < 16; ++j) acc[j] = fmaxf(acc[j], 0.0f);
  }
}

__device__ __forceinline__ void store4x4(float* dst, const float a[16]) {
#pragma unroll
  for (int q = 0; q < 4; ++q)
    *reinterpret_cast<float4*>(dst + q * 4) =
        make_float4(a[q * 4], a[q * 4 + 1], a[q * 4 + 2], a[q * 4 + 3]);
}

__device__ __forceinline__ void store16h(_Float16* dst, const float a[16]) {
  half8 h0, h1;
#pragma unroll
  for (int u = 0; u < 8; ++u) {
    h0[u] = (_Float16)a[u];
    h1[u] = (_Float16)a[8 + u];
  }
  *reinterpret_cast<half8*>(dst) = h0;
  *reinterpret_cast<half8*>(dst + 8) = h1;
}

// ---- weight prep: wt[m][j][k] = (f16)W_m[k][j]  (transposed, fp16) ----
__global__ __launch_bounds__(256) void wconv_kernel(const float* __restrict__ Wp2,
                                                    const float* __restrict__ Wa1,
                                                    const float* __restrict__ Wa2,
                                                    _Float16* __restrict__ wt) {
  int t = blockIdx.x * 256 + threadIdx.x;
  if (t >= 3 * 4096) return;
  int m = t >> 12, idx = t & 4095;
  int j = idx >> 6, k = idx & 63;
  const float* W = (m == 0) ? Wp2 : ((m == 1) ? Wa1 : Wa2);
  wt[m * 4096 + j * 64 + k] = (_Float16)W[k * 64 + j];
}

// ---- CSR build: histogram -> 3-kernel parallel scan -> scatter ----
__global__ __launch_bounds__(256) void hist_kernel(const int* __restrict__ ei,
                                                   int* __restrict__ counts) {
  int e = blockIdx.x * 256 + threadIdx.x;
  if (e < N_EDGES) atomicAdd(&counts[ei[N_EDGES + e]], 1);
}

// S1: per-block exclusive scan (1024 elems) + block totals
__global__ __launch_bounds__(1024) void scan1_kernel(const int* __restrict__ counts,
                                                     int* __restrict__ pexcl,
                                                     int* __restrict__ btot) {
  __shared__ int wsum[16];
  const int tid = threadIdx.x, lane = tid & 63, wid = tid >> 6;
  const int idx = blockIdx.x * 1024 + tid;
  const int val = (idx < N_NODES) ? counts[idx] : 0;
  int x = val;
#pragma unroll
  for (int o = 1; o < 64; o <<= 1) {
    int y = __shfl_up(x, o);
    if (lane >= o) x += y;
  }
  if (lane == 63) wsum[wid] = x;
  __syncthreads();
  if (wid == 0) {
    int s = (lane < 16) ? wsum[lane] : 0;
#pragma unroll
    for (int o = 1; o < 16; o <<= 1) {
      int y = __shfl_up(s, o);
      if (lane >= o) s += y;
    }
    if (lane < 16) wsum[lane] = s;
  }
  __syncthreads();
  const int woff = (wid > 0) ? wsum[wid - 1] : 0;
  const int incl = woff + x;
  if (idx < N_NODES) pexcl[idx] = incl - val;
  if (tid == 1023) btot[blockIdx.x] = incl;
}

// S2: single wave exclusive-scans the 98 block totals in place
__global__ __launch_bounds__(64) void scan2_kernel(int* __restrict__ btot) {
  const int lane = threadIdx.x;
  int carry = 0;
  for (int base = 0; base < N_SCAN_BLOCKS; base += 64) {
    const int ii = base + lane;
    const int v = (ii < N_SCAN_BLOCKS) ? btot[ii] : 0;
    int x = v;
#pragma unroll
    for (int o = 1; o < 64; o <<= 1) {
      int y = __shfl_up(x, o);
      if (lane >= o) x += y;
    }
    if (ii < N_SCAN_BLOCKS) btot[ii] = carry + x - v;  // exclusive
    carry += __shfl(x, 63);
  }
}

// S3: cursor = per-block exclusive + block offset
__global__ __launch_bounds__(256) void scan3_kernel(const int* __restrict__ pexcl,
                                                    const int* __restrict__ btot,
                                                    int* __restrict__ cursor) {
  const int idx = blockIdx.x * 256 + threadIdx.x;
  if (idx < N_NODES) cursor[idx] = pexcl[idx] + btot[idx >> 10];
}

__global__ __launch_bounds__(256) void scatter_kernel(const int* __restrict__ ei,
                                                      int* __restrict__ cursor,
                                                      int2* __restrict__ order2) {
  int e = blockIdx.x * 256 + threadIdx.x;
  if (e < N_EDGES) {
    int s = ei[e];
    int d = ei[N_EDGES + e];
    int p = atomicAdd(&cursor[d], 1);
    order2[p] = make_int2(s, d);
  }
}

// ---- Kernel A: h = relu(x@W_in+b_in); ad=h@W_dst; as=h@W_src; v=h@W_lin (fp16 out)
__global__ __launch_bounds__(256) void node_proj_kernel(
    const float* __restrict__ x, const float* __restrict__ W_in,
    const float* __restrict__ b_in, const float* __restrict__ W_lin,
    const float* __restrict__ W_src, const float* __restrict__ W_dst,
    _Float16* __restrict__ adh, _Float16* __restrict__ ash,
    _Float16* __restrict__ vh) {
  __shared__ __align__(16) float A[64 * PITCH];
  const int tid = threadIdx.x, lane = tid & 63, c0 = wave_c0();
  const int n0 = blockIdx.x * 64;
#pragma unroll
  for (int i = 0; i < 4; ++i) {
    int idx4 = tid + i * 256;
    int e = idx4 >> 4, k4 = (idx4 & 15) * 4;
    int n = n0 + e;
    float4 val = make_float4(0.f, 0.f, 0.f, 0.f);
    if (n < N_NODES) val = *reinterpret_cast<const float4*>(x + (size_t)n * 64 + k4);
    *reinterpret_cast<float4*>(&A[e * PITCH + k4]) = val;
  }
  __syncthreads();
  float h[16];
  wave_gemm16<true, true>(A, lane, c0, W_in, b_in, h);
  __syncthreads();
  store4x4(&A[lane * PITCH + c0], h);
  __syncthreads();
  float o1[16], o2[16], o3[16];
  wave_gemm16<false, false>(A, lane, c0, W_dst, nullptr, o1);
  wave_gemm16<false, false>(A, lane, c0, W_src, nullptr, o2);
  wave_gemm16<false, false>(A, lane, c0, W_lin, nullptr, o3);
  const int n = n0 + lane;
  if (n < N_NODES) {
    store16h(adh + (size_t)n * 64 + c0, o1);
    store16h(ash + (size_t)n * 64 + c0, o2);
    store16h(vh + (size_t)n * 64 + c0, o3);
  }
}

// MFMA helper: A-frag row = 16w + (lane&15), k = 8*(lane>>4)+e (+32).
// D: row = 16w + 4*(lane>>4)+r, col = 16t + (lane&15).
__device__ __forceinline__ void mfma3(const _Float16* aL, int w, int g, int a,
                                      const _Float16* __restrict__ Wt,
                                      const float* __restrict__ bias,
                                      f32x4 acc[4]) {
  const half8 A0 = *reinterpret_cast<const half8*>(aL + (16 * w + a) * PITCHH + 8 * g);
  const half8 A1 = *reinterpret_cast<const half8*>(aL + (16 * w + a) * PITCHH + 32 + 8 * g);
#pragma unroll
  for (int t = 0; t < 4; ++t) {
    const half8 B0 = *reinterpret_cast<const half8*>(Wt + (16 * t + a) * 64 + 8 * g);
    const half8 B1 = *reinterpret_cast<const half8*>(Wt + (16 * t + a) * 64 + 32 + 8 * g);
    const float bv = bias[16 * t + a];
    f32x4 c = {bv, bv, bv, bv};
    c = __builtin_amdgcn_mfma_f32_16x16x32_f16(A0, B0, c, 0, 0, 0);
    c = __builtin_amdgcn_mfma_f32_16x16x32_f16(A1, B1, c, 0, 0, 0);
    acc[t] = c;
  }
}

// ---- Kernel B: wave-private edge pipeline; boundary partials -> pbuf (no atomics)
// pbuf layout per block: [slot(0=head,1=tail)][array(0=num,1=den)][64ch] fp32
// headd[b]: -1 = head segment complete; -2 = whole-block single segment; else d
// taild[b]: -1 = tail segment complete; else d
__global__ __launch_bounds__(256) void edge_kernel(
    const int2* __restrict__ order2, const float* __restrict__ pos,
    const float* __restrict__ Wp1, const float* __restrict__ bp1,
    const _Float16* __restrict__ wt, const float* __restrict__ bp2,
    const float* __restrict__ ba1, const float* __restrict__ ba2,
    const _Float16* __restrict__ adh, const _Float16* __restrict__ ash,
    const _Float16* __restrict__ vh, float* __restrict__ num,
    float* __restrict__ den, float* __restrict__ pbuf,
    int* __restrict__ headd, int* __restrict__ taild) {
  __shared__ _Float16 s_act[64 * PITCHH];    // hp -> a_in -> ha -> ex (wave-private rows)
  __shared__ _Float16 s_delta[64 * PITCHH];  // relu'd delta
  __shared__ _Float16 s_v[64 * PITCHH];      // gathered v rows
  const int tid = threadIdx.x, lane = tid & 63, w = tid >> 6;
  const int g = lane >> 4, a = lane & 15, c0 = w * 16;
  const int i = blockIdx.x * 64 + lane;  // sorted edge slot (E % 64 == 0)
  const int2 sd = order2[i];
  const int d = sd.y;                    // epilogue segment key
  // row-phase mapping: 4 threads per own-wave row (row er, quarter p)
  const int er = 16 * w + (lane >> 2);
  const int p = lane & 3;
  const int2 sd2 = order2[blockIdx.x * 64 + er];
  const int s2 = sd2.x, d2 = sd2.y;
  // prefetch node-row gathers NOW; consumed at a_in phase (overlap stage0+GEMM1)
  const _Float16* adr = adh + (size_t)d2 * 64 + 16 * p;
  const _Float16* asr = ash + (size_t)s2 * 64 + 16 * p;
  const _Float16* vr  = vh  + (size_t)s2 * 64 + 16 * p;
  const half8 ad0 = *reinterpret_cast<const half8*>(adr);
  const half8 ad1 = *reinterpret_cast<const half8*>(adr + 8);
  const half8 as0 = *reinterpret_cast<const half8*>(asr);
  const half8 as1 = *reinterpret_cast<const half8*>(asr + 8);
  const half8 v0  = *reinterpret_cast<const half8*>(vr);
  const half8 v1  = *reinterpret_cast<const half8*>(vr + 8);
  // boundary probes (partial-vs-complete decision)
  int dm1 = -1, dp1 = -1;
  if (lane == 0 && i > 0) dm1 = order2[i - 1].y;
  if (lane == 63 && i + 1 < N_EDGES) dp1 = order2[i + 1].y;
  dm1 = __shfl(dm1, 0);
  // stage0: hp(row er, ch 16p..16p+16) = relu(dpos@Wp1+bp1) -- wave-private rows
  {
    const float2 pd = reinterpret_cast<const float2*>(pos)[d2];
    const float2 ps = reinterpret_cast<const float2*>(pos)[s2];
    const float dx = pd.x - ps.x, dy = pd.y - ps.y;
    half8 h0, h1;
#pragma unroll
    for (int u = 0; u < 8; ++u) {
      const int j0 = 16 * p + u, j1 = 16 * p + 8 + u;
      h0[u] = (_Float16)fmaxf(fmaf(dx, Wp1[j0], fmaf(dy, Wp1[64 + j0], bp1[j0])), 0.f);
      h1[u] = (_Float16)fmaxf(fmaf(dx, Wp1[j1], fmaf(dy, Wp1[64 + j1], bp1[j1])), 0.f);
    }
    *reinterpret_cast<half8*>(&s_act[er * PITCHH + 16 * p]) = h0;
    *reinterpret_cast<half8*>(&s_act[er * PITCHH + 16 * p + 8]) = h1;
  }
  f32x4 acc[4];
  // GEMM1: delta = relu(hp@Wp2+bp2)  (own rows only; DS in-order per wave)
  mfma3(s_act, w, g, a, wt, bp2, acc);
#pragma unroll
  for (int t = 0; t < 4; ++t)
#pragma unroll
    for (int r = 0; r < 4; ++r)
      s_delta[(16 * w + 4 * g + r) * PITCHH + 16 * t + a] =
          (_Float16)fmaxf(acc[t][r], 0.f);
  // a_in = ad[d]-as[s]+delta -> s_act (overwrite hp); v -> s_v  (own rows)
  {
    const half8 dl0 = *reinterpret_cast<const half8*>(&s_delta[er * PITCHH + 16 * p]);
    const half8 dl1 = *reinterpret_cast<const half8*>(&s_delta[er * PITCHH + 16 * p + 8]);
    *reinterpret_cast<half8*>(&s_act[er * PITCHH + 16 * p]) = ad0 - as0 + dl0;
    *reinterpret_cast<half8*>(&s_act[er * PITCHH + 16 * p + 8]) = ad1 - as1 + dl1;
    *reinterpret_cast<half8*>(&s_v[er * PITCHH + 16 * p]) = v0;
    *reinterpret_cast<half8*>(&s_v[er * PITCHH + 16 * p + 8]) = v1;
  }
  // GEMM2: ha = relu(a_in@Wa1+ba1) -> s_act (own rows)
  mfma3(s_act, w, g, a, wt + 4096, ba1, acc);
#pragma unroll
  for (int t = 0; t < 4; ++t)
#pragma unroll
    for (int r = 0; r < 4; ++r)
      s_act[(16 * w + 4 * g + r) * PITCHH + 16 * t + a] =
          (_Float16)fmaxf(acc[t][r], 0.f);
  // GEMM3: aat = relu(ha@Wa2+ba2); ex = exp(aat) -> s_act (own rows, over ha)
  mfma3(s_act, w, g, a, wt + 2 * 4096, ba2, acc);
#pragma unroll
  for (int t = 0; t < 4; ++t)
#pragma unroll
    for (int r = 0; r < 4; ++r)
      s_act[(16 * w + 4 * g + r) * PITCHH + 16 * t + a] =
          (_Float16)__expf(fmaxf(acc[t][r], 0.f));
  __syncthreads();  // ONLY barrier: cross-wave rows of s_act(ex)/s_v/s_delta
  // epilogue (lane=edge, channels c0..c0+15)
  const half8 e0 = *reinterpret_cast<const half8*>(&s_act[lane * PITCHH + c0]);
  const half8 e1 = *reinterpret_cast<const half8*>(&s_act[lane * PITCHH + c0 + 8]);
  const half8 dl0 = *reinterpret_cast<const half8*>(&s_delta[lane * PITCHH + c0]);
  const half8 dl1 = *reinterpret_cast<const half8*>(&s_delta[lane * PITCHH + c0 + 8]);
  const half8 vv0 = *reinterpret_cast<const half8*>(&s_v[lane * PITCHH + c0]);
  const half8 vv1 = *reinterpret_cast<const half8*>(&s_v[lane * PITCHH + c0 + 8]);
  float vals[32];  // [0..15]=ex*(v+delta), [16..31]=ex
#pragma unroll
  for (int j = 0; j < 16; ++j) {
    const float ex = (float)((j < 8) ? e0[j] : e1[j - 8]);
    const float dj = (float)((j < 8) ? dl0[j] : dl1[j - 8]);
    const float vj = (float)((j < 8) ? vv0[j] : vv1[j - 8]);
    vals[j] = ex * (vj + dj);
    vals[16 + j] = ex;
  }
  // wave-level segmented inclusive scan over contiguous equal-d runs
  const int dprev = __shfl_up(d, 1);
  const int dnext = __shfl_down(d, 1);
  const bool head = (lane == 0) || (d != dprev);
  const bool tail = (lane == 63) || (d != dnext);
  const unsigned long long hb = __ballot(head);
  const unsigned long long maskle =
      (lane == 63) ? ~0ull : ((1ull << (lane + 1)) - 1ull);
  const int myhead = 63 - __clzll(hb & maskle);
#pragma unroll
  for (int o = 1; o < 64; o <<= 1) {
    const bool c = (lane - o) >= myhead;
#pragma unroll
    for (int t = 0; t < 32; ++t) {
      float y = __shfl_up(vals[t], o);
      if (c) vals[t] += y;
    }
  }
  if (tail) {
    const bool ts = (myhead > 0) || (dm1 != d);  // segment starts in this block
    const bool te = (lane < 63) || (dp1 != d);   // segment ends in this block
    if (ts && te) {
      // complete segment: exclusive writer of this (d, chunk) -> plain stores
      float* np = num + (size_t)d * 64 + c0;
      float* dp_ = den + (size_t)d * 64 + c0;
#pragma unroll
      for (int q = 0; q < 4; ++q)
        *reinterpret_cast<float4*>(np + 4 * q) =
            make_float4(vals[4 * q], vals[4 * q + 1], vals[4 * q + 2], vals[4 * q + 3]);
#pragma unroll
      for (int q = 0; q < 4; ++q)
        *reinterpret_cast<float4*>(dp_ + 4 * q) =
            make_float4(vals[16 + 4 * q], vals[17 + 4 * q], vals[18 + 4 * q],
                        vals[19 + 4 * q]);
    } else {
      // partial segment: coalesced dump to pbuf; resolved by finish_kernel
      const int slot = (!ts && te) ? 0 : 1;  // head -> 0; tail/whole -> 1
      float* pb = pbuf + (size_t)blockIdx.x * 256 + slot * 128 + c0;
#pragma unroll
      for (int q = 0; q < 4; ++q)
        *reinterpret_cast<float4*>(pb + 4 * q) =
            make_float4(vals[4 * q], vals[4 * q + 1], vals[4 * q + 2], vals[4 * q + 3]);
#pragma unroll
      for (int q = 0; q < 4; ++q)
        *reinterpret_cast<float4*>(pb + 64 + 4 * q) =
            make_float4(vals[16 + 4 * q], vals[17 + 4 * q], vals[18 + 4 * q],
                        vals[19 + 4 * q]);
    }
    // markers (wave 0 only; segment structure identical across waves)
    if (w == 0) {
      if (myhead == 0) headd[blockIdx.x] = ts ? -1 : (te ? d : -2);
      if (lane == 63) taild[blockIdx.x] = te ? -1 : d;
    }
  }
}

// ---- finish: resolve boundary partials. Thread block b handles boundary
// between edge-blocks b-1 and b; owns tail[b-1] and head[b]. ----
__global__ __launch_bounds__(128) void finish_kernel(
    const float* __restrict__ pbuf, const int* __restrict__ headd,
    const int* __restrict__ taild, float* __restrict__ num,
    float* __restrict__ den) {
  const int b = blockIdx.x + 1;  // 1..NB-1
  const int t = taild[b - 1];
  if (t < 0) return;  // tail segment of b-1 complete; h>=0 implies t==h, so no drop
  const int ch = threadIdx.x & 63, arr = threadIdx.x >> 6;
  const int h = headd[b];
  const float tv = pbuf[(size_t)(b - 1) * 256 + 128 + arr * 64 + ch];
  float* dst = (arr ? den : num) + (size_t)t * 64 + ch;
  if (h == t) {
    const float hv = pbuf[(size_t)b * 256 + arr * 64 + ch];
    if (headd[b - 1] != -2) {
      *dst = tv + hv;  // chain is exactly {b-1, b}: exclusive owner
    } else {
      atomicAdd(dst, tv + hv);  // chain extends left (degree > 64; ~never)
    }
  } else {
    // h == -2: block b is whole-block same-d -> chain continues right
    atomicAdd(dst, tv);
  }
}

// ---- Kernel C: out = relu((num/(den+1e-16)) @ W_out + b_out) ----
__global__ __launch_bounds__(256) void out_kernel(
    const float* __restrict__ num, const float* __restrict__ den,
    const float* __restrict__ W_out, const float* __restrict__ b_out,
    float* __restrict__ out) {
  __shared__ __align__(16) float A[64 * PITCH];
  const int tid = threadIdx.x, lane = tid & 63, c0 = wave_c0();
  const int n0 = blockIdx.x * 64;
#pragma unroll
  for (int i = 0; i < 4; ++i) {
    int idx4 = tid + i * 256;
    int e = idx4 >> 4, k4 = (idx4 & 15) * 4;
    int n = n0 + e;
    float4 val = make_float4(0.f, 0.f, 0.f, 0.f);
    if (n < N_NODES) {
      float4 nu = *reinterpret_cast<const float4*>(num + (size_t)n * 64 + k4);
      float4 de = *reinterpret_cast<const float4*>(den + (size_t)n * 64 + k4);
      val.x = nu.x / (de.x + 1e-16f);
      val.y = nu.y / (de.y + 1e-16f);
      val.z = nu.z / (de.z + 1e-16f);
      val.w = nu.w / (de.w + 1e-16f);
    }
    *reinterpret_cast<float4*>(&A[e * PITCH + k4]) = val;
  }
  __syncthreads();
  float o[16];
  wave_gemm16<true, true>(A, lane, c0, W_out, b_out, o);
  const int n = n0 + lane;
  if (n < N_NODES) store4x4(out + (size_t)n * 64 + c0, o);
}

extern "C" void kernel_launch(void* const* d_in, const int* in_sizes, int n_in,
                              void* d_out, int out_size, void* d_ws,
                              size_t ws_size, hipStream_t stream) {
  const float* x     = (const float*)d_in[0];
  const float* pos   = (const float*)d_in[1];
  const int*   ei    = (const int*)d_in[2];
  const float* W_in  = (const float*)d_in[3];
  const float* b_in  = (const float*)d_in[4];
  const float* W_lin = (const float*)d_in[5];
  const float* W_src = (const float*)d_in[6];
  const float* W_dst = (const float*)d_in[7];
  const float* Wp1   = (const float*)d_in[8];
  const float* bp1   = (const float*)d_in[9];
  const float* Wp2   = (const float*)d_in[10];
  const float* bp2   = (const float*)d_in[11];
  const float* Wa1   = (const float*)d_in[12];
  const float* ba1   = (const float*)d_in[13];
  const float* Wa2   = (const float*)d_in[14];
  const float* ba2   = (const float*)d_in[15];
  const float* W_out = (const float*)d_in[16];
  const float* b_out = (const float*)d_in[17];
  float* out = (float*)d_out;

  const size_t NC = (size_t)N_NODES * 64;
  _Float16* adh = (_Float16*)d_ws;               // NC halfs
  _Float16* ash = adh + NC;                      // NC halfs
  _Float16* vh  = ash + NC;                      // NC halfs
  float* num = (float*)(vh + NC);                // NC floats
  float* den = num + NC;                         // NC floats
  int* counts = (int*)(den + NC);                // N_NODES ints
  int* cursor = counts + N_NODES;                // N_NODES ints
  int* pexcl  = cursor + N_NODES;                // N_NODES ints
  int* btot   = pexcl + N_NODES;                 // 128 ints
  int2* order2 = (int2*)(btot + 128);            // N_EDGES int2 (8B aligned)
  float* pbuf  = (float*)(order2 + N_EDGES);     // NB*256 floats (partials)
  int* headd   = (int*)(pbuf + (size_t)NB * 256);// NB ints
  int* taild   = headd + NB;                     // NB ints
  _Float16* wt = (_Float16*)(taild + NB);        // 3*4096 f16 (16B aligned)

  hipMemsetAsync(num, 0, 2 * NC * sizeof(float), stream);    // num+den
  hipMemsetAsync(counts, 0, N_NODES * sizeof(int), stream);  // histogram

  wconv_kernel<<<48, 256, 0, stream>>>(Wp2, Wa1, Wa2, wt);
  hist_kernel<<<(N_EDGES + 255) / 256, 256, 0, stream>>>(ei, counts);
  scan1_kernel<<<N_SCAN_BLOCKS, 1024, 0, stream>>>(counts, pexcl, btot);
  scan2_kernel<<<1, 64, 0, stream>>>(btot);
  scan3_kernel<<<(N_NODES + 255) / 256, 256, 0, stream>>>(pexcl, btot, cursor);
  scatter_kernel<<<(N_EDGES + 255) / 256, 256, 0, stream>>>(ei, cursor, order2);

  node_proj_kernel<<<(N_NODES + 63) / 64, 256, 0, stream>>>(
      x, W_in, b_in, W_lin, W_src, W_dst, adh, ash, vh);
  edge_kernel<<<NB, 256, 0, stream>>>(
      order2, pos, Wp1, bp1, wt, bp2, ba1, ba2, adh, ash, vh, num, den,
      pbuf, headd, taild);
  finish_kernel<<<NB - 1, 128, 0, stream>>>(pbuf, headd, taild, num, den);
  out_kernel<<<(N_NODES + 63) / 64, 256, 0, stream>>>(num, den, W_out, b_out, out);
}